// Round 1
// baseline (626.963 us; speedup 1.0000x reference)
//
#include <hip/hip_runtime.h>
#include <cstdint>

#define LTOK 12544
#define BATCH 2
#define CDIM 128
#define C3 384
#define RES 112
#define NROWS (BATCH * LTOK)  // 25088
#define SCALE 0.17677669529663687f  // 1/sqrt(32)

// map window-local token n -> (i, j); branch 0: W_sp=7, branch 1: W_sp=112
__device__ inline void nij(int n, int branch, int& i, int& j) {
    if (branch == 0) { i = n / 7; j = n - i * 7; }
    else             { i = n / 112; j = n - i * 112; }
}

// ---------------- K1: LN1 + QKV GEMM (8 rows / 128-thread block) ----------------
__global__ __launch_bounds__(128) void k_ln_qkv(const float* __restrict__ x,
        const float* __restrict__ g1, const float* __restrict__ b1,
        const float* __restrict__ wqkv, float* __restrict__ qkv)
{
    __shared__ float xs[8][128];
    __shared__ float img[8][128];
    const int tid = threadIdx.x;
    const long long row0 = (long long)blockIdx.x * 8;

    const float4* xg = (const float4*)(x + row0 * CDIM);
    float4* xs4 = (float4*)&xs[0][0];
    for (int i = tid; i < 256; i += 128) xs4[i] = xg[i];
    __syncthreads();

    // LayerNorm: 16 threads per row
    const int r = tid >> 4, l16 = tid & 15;
    float s = 0.f, s2 = 0.f;
    #pragma unroll
    for (int cc = 0; cc < 8; ++cc) {
        float v = xs[r][l16 * 8 + cc];
        s += v; s2 += v * v;
    }
    #pragma unroll
    for (int m = 8; m >= 1; m >>= 1) { s += __shfl_xor(s, m, 16); s2 += __shfl_xor(s2, m, 16); }
    const float mean = s * (1.f / 128.f);
    const float var = s2 * (1.f / 128.f) - mean * mean;
    const float rs = rsqrtf(var + 1e-5f);
    #pragma unroll
    for (int cc = 0; cc < 8; ++cc) {
        int c = l16 * 8 + cc;
        img[r][c] = (xs[r][c] - mean) * rs * g1[c] + b1[c];
    }
    __syncthreads();

    // each thread computes outputs j = tid + 128*p for all 8 rows
    for (int p = 0; p < 3; ++p) {
        const int j = tid + (p << 7);
        const float4* wr = (const float4*)(wqkv + (long long)j * CDIM);
        float acc[8];
        #pragma unroll
        for (int rr = 0; rr < 8; ++rr) acc[rr] = 0.f;
        #pragma unroll 8
        for (int dc = 0; dc < 32; ++dc) {
            float4 w4 = wr[dc];
            #pragma unroll
            for (int rr = 0; rr < 8; ++rr) {
                const float* ip = &img[rr][dc * 4];
                acc[rr] += w4.x * ip[0] + w4.y * ip[1] + w4.z * ip[2] + w4.w * ip[3];
            }
        }
        #pragma unroll
        for (int rr = 0; rr < 8; ++rr)
            qkv[(row0 + rr) * C3 + j] = acc[rr];
    }
}

// ---------------- K2: windowed attention + LEPE ----------------
// grid.x = 128 window-heads (branch*64 + (b*16+w)*2 + head), grid.y = 4 q-tiles of 196 rows
__global__ __launch_bounds__(256) void k_attn(const float* __restrict__ qkv,
        const float* __restrict__ cw0, const float* __restrict__ cb0,
        const float* __restrict__ cw1, const float* __restrict__ cb1,
        float* __restrict__ att)
{
    __shared__ float ks[112 * 32];
    __shared__ float vs[112 * 32];
    const int tid = threadIdx.x;
    const int wh = blockIdx.x;
    const int branch = wh >> 6;
    const int idx = wh & 63;
    const int win = idx >> 1, head = idx & 1;
    const int b = win >> 4, w = win & 15;
    const int rowBase = branch ? w * 7 : 0;
    const int colBase = branch ? 0 : w * 7;
    const float* cw = branch ? cw1 : cw0;
    const float* cb = branch ? cb1 : cb0;
    const int cbase = branch * 64 + head * 32;
    const long long qkvB = (long long)b * LTOK * C3;

    const int n0 = blockIdx.y * 196 + tid;
    const bool active = (tid < 196);

    float q[32], O[32];
    float mx = -1e30f, l = 0.f;
    int i0 = 0, j0 = 0;
    if (active) {
        nij(n0, branch, i0, j0);
        const long long Lq = (long long)(rowBase + i0) * RES + colBase + j0;
        const float4* qp = (const float4*)(qkv + qkvB + Lq * C3 + cbase);
        #pragma unroll
        for (int d4 = 0; d4 < 8; ++d4) {
            float4 v = qp[d4];
            q[d4 * 4 + 0] = v.x * SCALE; q[d4 * 4 + 1] = v.y * SCALE;
            q[d4 * 4 + 2] = v.z * SCALE; q[d4 * 4 + 3] = v.w * SCALE;
        }
        #pragma unroll
        for (int d = 0; d < 32; ++d) O[d] = 0.f;
    }

    for (int cc = 0; cc < 7; ++cc) {
        __syncthreads();  // previous chunk fully consumed
        // stage K and V chunk (112 rows x 32) as float4
        for (int t = tid; t < 1792; t += 256) {
            const int isV = (t >= 896);
            const int tt = isV ? t - 896 : t;
            const int rr = tt >> 3, d4 = tt & 7;
            const int n = cc * 112 + rr;
            int i, j; nij(n, branch, i, j);
            const long long Lk = (long long)(rowBase + i) * RES + colBase + j;
            const float4* src = (const float4*)(qkv + qkvB + Lk * C3 + (isV ? 256 : 128) + cbase);
            float4* dst = (float4*)(isV ? vs : ks);
            dst[rr * 8 + d4] = src[d4];
        }
        __syncthreads();
        if (active) {
            for (int jj = 0; jj < 112; ++jj) {
                const float* kr = &ks[jj * 32];
                float s = 0.f;
                #pragma unroll
                for (int d = 0; d < 32; ++d) s += q[d] * kr[d];
                if (s > mx) {
                    const float rsc = __expf(mx - s);
                    l *= rsc;
                    #pragma unroll
                    for (int d = 0; d < 32; ++d) O[d] *= rsc;
                    mx = s;
                }
                const float e = __expf(s - mx);
                l += e;
                const float* vr = &vs[jj * 32];
                #pragma unroll
                for (int d = 0; d < 32; ++d) O[d] += e * vr[d];
            }
        }
    }

    if (active) {
        const float inv = 1.f / l;
        #pragma unroll
        for (int d = 0; d < 32; ++d) O[d] *= inv;
        // LEPE: depthwise 3x3 conv on v within the window (zero SAME padding)
        const int H_sp = branch ? 7 : RES;
        const int W_sp = branch ? RES : 7;
        #pragma unroll
        for (int dij = 0; dij < 9; ++dij) {
            const int di = dij / 3 - 1, dj = dij % 3 - 1;
            const int ii = i0 + di, jj2 = j0 + dj;
            if (ii < 0 || ii >= H_sp || jj2 < 0 || jj2 >= W_sp) continue;
            const long long Ln = (long long)(rowBase + ii) * RES + colBase + jj2;
            const float* vp = qkv + qkvB + Ln * C3 + 256 + cbase;
            #pragma unroll
            for (int d = 0; d < 32; ++d)
                O[d] += cw[(head * 32 + d) * 9 + dij] * vp[d];
        }
        const long long Lq = (long long)(rowBase + i0) * RES + colBase + j0;
        float* op = att + ((long long)b * LTOK + Lq) * CDIM + cbase;
        #pragma unroll
        for (int d = 0; d < 32; ++d) op[d] = O[d] + cb[head * 32 + d];
    }
}

// ---------------- K3: proj + bias + residual ----------------
__global__ __launch_bounds__(128) void k_proj(const float* __restrict__ att,
        const float* __restrict__ wproj, const float* __restrict__ bproj,
        const float* __restrict__ x, float* __restrict__ xmid)
{
    __shared__ float as_[8][128];
    const int tid = threadIdx.x;
    const long long row0 = (long long)blockIdx.x * 8;
    const float4* ag = (const float4*)(att + row0 * CDIM);
    float4* as4 = (float4*)&as_[0][0];
    for (int i = tid; i < 256; i += 128) as4[i] = ag[i];
    __syncthreads();

    const float4* wr = (const float4*)(wproj + (long long)tid * CDIM);
    float acc[8];
    #pragma unroll
    for (int rr = 0; rr < 8; ++rr) acc[rr] = 0.f;
    #pragma unroll 8
    for (int dc = 0; dc < 32; ++dc) {
        float4 w4 = wr[dc];
        #pragma unroll
        for (int rr = 0; rr < 8; ++rr) {
            const float* ip = &as_[rr][dc * 4];
            acc[rr] += w4.x * ip[0] + w4.y * ip[1] + w4.z * ip[2] + w4.w * ip[3];
        }
    }
    const float bb = bproj[tid];
    #pragma unroll
    for (int rr = 0; rr < 8; ++rr)
        xmid[(row0 + rr) * CDIM + tid] = x[(row0 + rr) * CDIM + tid] + acc[rr] + bb;
}

// ---------------- K4: LN2 + FC1 + GELU + FC2 + residual ----------------
__global__ __launch_bounds__(128) void k_mlp(const float* __restrict__ xmid,
        const float* __restrict__ g2, const float* __restrict__ b2,
        const float* __restrict__ wfc1, const float* __restrict__ bfc1,
        const float* __restrict__ wfc2, const float* __restrict__ bfc2,
        float* __restrict__ out)
{
    __shared__ float xs[8][128];
    __shared__ float ys[8][128];
    __shared__ float hs[8][512];
    const int tid = threadIdx.x;
    const long long row0 = (long long)blockIdx.x * 8;

    const float4* xg = (const float4*)(xmid + row0 * CDIM);
    float4* xs4 = (float4*)&xs[0][0];
    for (int i = tid; i < 256; i += 128) xs4[i] = xg[i];
    __syncthreads();

    const int r = tid >> 4, l16 = tid & 15;
    float s = 0.f, s2 = 0.f;
    #pragma unroll
    for (int cc = 0; cc < 8; ++cc) {
        float v = xs[r][l16 * 8 + cc];
        s += v; s2 += v * v;
    }
    #pragma unroll
    for (int m = 8; m >= 1; m >>= 1) { s += __shfl_xor(s, m, 16); s2 += __shfl_xor(s2, m, 16); }
    const float mean = s * (1.f / 128.f);
    const float var = s2 * (1.f / 128.f) - mean * mean;
    const float rs = rsqrtf(var + 1e-5f);
    #pragma unroll
    for (int cc = 0; cc < 8; ++cc) {
        int c = l16 * 8 + cc;
        ys[r][c] = (xs[r][c] - mean) * rs * g2[c] + b2[c];
    }
    __syncthreads();

    // FC1 + exact GELU: each thread does j = tid + 128*p, p in 0..3
    for (int p = 0; p < 4; ++p) {
        const int j = tid + (p << 7);
        const float4* wr = (const float4*)(wfc1 + (long long)j * CDIM);
        float acc[8];
        const float bj = bfc1[j];
        #pragma unroll
        for (int rr = 0; rr < 8; ++rr) acc[rr] = bj;
        #pragma unroll 8
        for (int dc = 0; dc < 32; ++dc) {
            float4 w4 = wr[dc];
            #pragma unroll
            for (int rr = 0; rr < 8; ++rr) {
                const float* ip = &ys[rr][dc * 4];
                acc[rr] += w4.x * ip[0] + w4.y * ip[1] + w4.z * ip[2] + w4.w * ip[3];
            }
        }
        #pragma unroll
        for (int rr = 0; rr < 8; ++rr) {
            float a = acc[rr];
            hs[rr][j] = 0.5f * a * (1.0f + erff(a * 0.70710678118654752f));
        }
    }
    __syncthreads();

    // FC2 + residual: thread computes channel tid for 8 rows
    const float4* wr2 = (const float4*)(wfc2 + (long long)tid * 512);
    float acc2[8];
    const float bc = bfc2[tid];
    #pragma unroll
    for (int rr = 0; rr < 8; ++rr) acc2[rr] = bc + xs[rr][tid];
    #pragma unroll 8
    for (int dc = 0; dc < 128; ++dc) {
        float4 w4 = wr2[dc];
        #pragma unroll
        for (int rr = 0; rr < 8; ++rr) {
            const float* ip = &hs[rr][dc * 4];
            acc2[rr] += w4.x * ip[0] + w4.y * ip[1] + w4.z * ip[2] + w4.w * ip[3];
        }
    }
    #pragma unroll
    for (int rr = 0; rr < 8; ++rr)
        out[(row0 + rr) * CDIM + tid] = acc2[rr];
}

extern "C" void kernel_launch(void* const* d_in, const int* in_sizes, int n_in,
                              void* d_out, int out_size, void* d_ws, size_t ws_size,
                              hipStream_t stream) {
    const float* x     = (const float*)d_in[0];
    const float* g1    = (const float*)d_in[1];
    const float* b1    = (const float*)d_in[2];
    const float* wqkv  = (const float*)d_in[3];
    const float* cw0   = (const float*)d_in[4];
    const float* cb0   = (const float*)d_in[5];
    const float* cw1   = (const float*)d_in[6];
    const float* cb1   = (const float*)d_in[7];
    const float* wproj = (const float*)d_in[8];
    const float* bproj = (const float*)d_in[9];
    const float* g2    = (const float*)d_in[10];
    const float* b2    = (const float*)d_in[11];
    const float* wfc1  = (const float*)d_in[12];
    const float* bfc1  = (const float*)d_in[13];
    const float* wfc2  = (const float*)d_in[14];
    const float* bfc2  = (const float*)d_in[15];

    float* ws   = (float*)d_ws;
    float* qkv  = ws;                       // 25088*384 = 9,633,792 floats
    float* att  = qkv + (size_t)NROWS * C3; // 3,211,264 floats
    float* xmid = att + (size_t)NROWS * CDIM;

    float* out = (float*)d_out;

    k_ln_qkv<<<NROWS / 8, 128, 0, stream>>>(x, g1, b1, wqkv, qkv);
    k_attn<<<dim3(128, 4), 256, 0, stream>>>(qkv, cw0, cb0, cw1, cb1, att);
    k_proj<<<NROWS / 8, 128, 0, stream>>>(att, wproj, bproj, x, xmid);
    k_mlp<<<NROWS / 8, 128, 0, stream>>>(xmid, g2, b2, wfc1, bfc1, wfc2, bfc2, out);
}

// Round 2
// 391.365 us; speedup vs baseline: 1.6020x; 1.6020x over previous
//
#include <hip/hip_runtime.h>
#include <cstdint>

#define LTOK 12544
#define BATCH 2
#define CDIM 128
#define C3 384
#define RES 112
#define NROWS (BATCH * LTOK)  // 25088
#define SCALE 0.17677669529663687f  // 1/sqrt(32)

typedef __attribute__((ext_vector_type(8))) short bf16x8;
typedef __attribute__((ext_vector_type(4))) float f32x4;

__device__ inline ushort f2b(float f) {
    union { float f; unsigned u; } v; v.f = f;
    unsigned r = (v.u + 0x7FFFu + ((v.u >> 16) & 1u)) >> 16;
    return (ushort)r;
}

// map window-local token n -> (i, j); branch 0: W_sp=7, branch 1: W_sp=112
__device__ inline void nij(int n, int branch, int& i, int& j) {
    if (branch == 0) { i = n / 7; j = n - i * 7; }
    else             { i = n / 112; j = n - i * 112; }
}

// ---------------- K1: LN1 + QKV GEMM (8 rows / 128-thread block) ----------------
__global__ __launch_bounds__(128) void k_ln_qkv(const float* __restrict__ x,
        const float* __restrict__ g1, const float* __restrict__ b1,
        const float* __restrict__ wqkv, float* __restrict__ qkv)
{
    __shared__ float xs[8][128];
    __shared__ float img[8][128];
    const int tid = threadIdx.x;
    const long long row0 = (long long)blockIdx.x * 8;

    const float4* xg = (const float4*)(x + row0 * CDIM);
    float4* xs4 = (float4*)&xs[0][0];
    for (int i = tid; i < 256; i += 128) xs4[i] = xg[i];
    __syncthreads();

    const int r = tid >> 4, l16 = tid & 15;
    float s = 0.f, s2 = 0.f;
    #pragma unroll
    for (int cc = 0; cc < 8; ++cc) {
        float v = xs[r][l16 * 8 + cc];
        s += v; s2 += v * v;
    }
    #pragma unroll
    for (int m = 8; m >= 1; m >>= 1) { s += __shfl_xor(s, m, 16); s2 += __shfl_xor(s2, m, 16); }
    const float mean = s * (1.f / 128.f);
    const float var = s2 * (1.f / 128.f) - mean * mean;
    const float rs = rsqrtf(var + 1e-5f);
    #pragma unroll
    for (int cc = 0; cc < 8; ++cc) {
        int c = l16 * 8 + cc;
        img[r][c] = (xs[r][c] - mean) * rs * g1[c] + b1[c];
    }
    __syncthreads();

    for (int p = 0; p < 3; ++p) {
        const int j = tid + (p << 7);
        const float4* wr = (const float4*)(wqkv + (long long)j * CDIM);
        float acc[8];
        #pragma unroll
        for (int rr = 0; rr < 8; ++rr) acc[rr] = 0.f;
        #pragma unroll 8
        for (int dc = 0; dc < 32; ++dc) {
            float4 w4 = wr[dc];
            #pragma unroll
            for (int rr = 0; rr < 8; ++rr) {
                const float* ip = &img[rr][dc * 4];
                acc[rr] += w4.x * ip[0] + w4.y * ip[1] + w4.z * ip[2] + w4.w * ip[3];
            }
        }
        #pragma unroll
        for (int rr = 0; rr < 8; ++rr)
            qkv[(row0 + rr) * C3 + j] = acc[rr];
    }
}

// ---------------- K2: windowed attention + LEPE via bf16 MFMA ----------------
// grid = (128 window-heads, 7 q-tile-groups), 256 threads (4 waves).
// Per block: stages all 784 keys of its window in 7 chunks of 112;
// waves 0-2 own 2 q-tiles of 16 rows, wave 3 owns 1 (7 tiles/block, 49/window-head).
__global__ __launch_bounds__(256) void k_attn_mfma(const float* __restrict__ qkv,
        const float* __restrict__ cw0, const float* __restrict__ cb0,
        const float* __restrict__ cw1, const float* __restrict__ cb1,
        float* __restrict__ att)
{
    __shared__ __align__(16) ushort ks[112 * 40];    // K chunk, row-major [key][32+8]
    __shared__ __align__(16) ushort vt[32 * 136];    // V chunk, transposed [d][128+8], cols 112..127 zero
    __shared__ __align__(16) ushort pl[4][16 * 40];  // per-wave P tile [q][32+8]
    __shared__ __align__(16) float  ol[4][16 * 36];  // per-wave O tile [q][32+4]

    const int tid = threadIdx.x;
    const int wv = tid >> 6, lane = tid & 63;
    const int g = lane >> 4, c16 = lane & 15;

    const int wh = blockIdx.x;
    const int branch = wh >> 6;
    const int idx = wh & 63;
    const int win = idx >> 1, head = idx & 1;
    const int b = win >> 4, w = win & 15;
    const int rowBase = branch ? w * 7 : 0;
    const int colBase = branch ? 0 : w * 7;
    const float* cw = branch ? cw1 : cw0;
    const float* cb = branch ? cb1 : cb0;
    const int cbase = branch * 64 + head * 32;
    const long long qkvB = (long long)b * LTOK * C3;

    // zero-fill vt pad cols [112,128) once: 32 rows x 8 u32 = 256 units
    {
        const int row = tid >> 3, cwd = tid & 7;
        *(unsigned*)&vt[row * 136 + 112 + cwd * 2] = 0u;
    }

    const int t0 = blockIdx.y * 7 + 2 * wv;      // first q-tile (global, 0..48)
    const int nt = (2 * wv + 1 < 7) ? 2 : 1;     // wave 3 has 1 tile

    // load Q fragments (lane: q-row = c16 of tile, d = g*8..g*8+7)
    bf16x8 qf[2];
    #pragma unroll
    for (int t = 0; t < 2; ++t) if (t < nt) {
        int n = (t0 + t) * 16 + c16;
        int i, j; nij(n, branch, i, j);
        const float* qp = qkv + qkvB + (long long)((rowBase + i) * RES + colBase + j) * C3 + cbase + g * 8;
        float4 a0 = *(const float4*)qp;
        float4 a1 = *(const float4*)(qp + 4);
        bf16x8 qq;
        qq[0] = (short)f2b(a0.x * SCALE); qq[1] = (short)f2b(a0.y * SCALE);
        qq[2] = (short)f2b(a0.z * SCALE); qq[3] = (short)f2b(a0.w * SCALE);
        qq[4] = (short)f2b(a1.x * SCALE); qq[5] = (short)f2b(a1.y * SCALE);
        qq[6] = (short)f2b(a1.z * SCALE); qq[7] = (short)f2b(a1.w * SCALE);
        qf[t] = qq;
    }

    f32x4 O00 = {0.f,0.f,0.f,0.f}, O01 = {0.f,0.f,0.f,0.f};
    f32x4 O10 = {0.f,0.f,0.f,0.f}, O11 = {0.f,0.f,0.f,0.f};
    float lsum0[4] = {0.f,0.f,0.f,0.f};
    float lsum1[4] = {0.f,0.f,0.f,0.f};

    for (int cc = 0; cc < 7; ++cc) {
        __syncthreads();   // previous chunk fully consumed
        // stage 112 keys: K row-major bf16, V transposed bf16
        for (int u = tid; u < 896; u += 256) {
            const int key = u >> 3, d4 = u & 7;
            const int n = cc * 112 + key;
            int i, j; nij(n, branch, i, j);
            const float* base = qkv + qkvB + (long long)((rowBase + i) * RES + colBase + j) * C3 + cbase + d4 * 4;
            float4 kk = *(const float4*)(base + 128);
            float4 vv = *(const float4*)(base + 256);
            ushort4 k4;
            k4.x = f2b(kk.x); k4.y = f2b(kk.y); k4.z = f2b(kk.z); k4.w = f2b(kk.w);
            *(ushort4*)&ks[key * 40 + d4 * 4] = k4;
            vt[(d4 * 4 + 0) * 136 + key] = f2b(vv.x);
            vt[(d4 * 4 + 1) * 136 + key] = f2b(vv.y);
            vt[(d4 * 4 + 2) * 136 + key] = f2b(vv.z);
            vt[(d4 * 4 + 3) * 136 + key] = f2b(vv.w);
        }
        __syncthreads();

        // 4 key-pairs of 32 (pair 3 = tile 6 + zero pad)
        #pragma unroll
        for (int p = 0; p < 4; ++p) {
            bf16x8 kf0 = *(const bf16x8*)&ks[(p * 32 + c16) * 40 + g * 8];
            bf16x8 kf1;
            if (p < 3) kf1 = *(const bf16x8*)&ks[(p * 32 + 16 + c16) * 40 + g * 8];
            bf16x8 vf0 = *(const bf16x8*)&vt[c16 * 136 + p * 32 + g * 8];
            bf16x8 vf1 = *(const bf16x8*)&vt[(16 + c16) * 136 + p * 32 + g * 8];
            ushort* pb = &pl[wv][0];

            #pragma unroll
            for (int t = 0; t < 2; ++t) if (t < nt) {
                const bf16x8 qq = t ? qf[1] : qf[0];
                f32x4 z = {0.f,0.f,0.f,0.f};
                f32x4 S0 = __builtin_amdgcn_mfma_f32_16x16x32_bf16(qq, kf0, z, 0, 0, 0);
                f32x4 S1 = z;
                if (p < 3) S1 = __builtin_amdgcn_mfma_f32_16x16x32_bf16(qq, kf1, z, 0, 0, 0);
                ushort pw0[4], pw1[4];
                #pragma unroll
                for (int r = 0; r < 4; ++r) {
                    float e0 = __expf(S0[r]);
                    if (t) lsum1[r] += e0; else lsum0[r] += e0;
                    pw0[r] = f2b(e0);
                    if (p < 3) {
                        float e1 = __expf(S1[r]);
                        if (t) lsum1[r] += e1; else lsum0[r] += e1;
                        pw1[r] = f2b(e1);
                    } else pw1[r] = 0;
                }
                #pragma unroll
                for (int r = 0; r < 4; ++r) {
                    pb[(g * 4 + r) * 40 + c16]      = pw0[r];
                    pb[(g * 4 + r) * 40 + 16 + c16] = pw1[r];
                }
                bf16x8 pf = *(const bf16x8*)&pb[c16 * 40 + g * 8];
                if (t) {
                    O10 = __builtin_amdgcn_mfma_f32_16x16x32_bf16(pf, vf0, O10, 0, 0, 0);
                    O11 = __builtin_amdgcn_mfma_f32_16x16x32_bf16(pf, vf1, O11, 0, 0, 0);
                } else {
                    O00 = __builtin_amdgcn_mfma_f32_16x16x32_bf16(pf, vf0, O00, 0, 0, 0);
                    O01 = __builtin_amdgcn_mfma_f32_16x16x32_bf16(pf, vf1, O01, 0, 0, 0);
                }
            }
        }
    }

    // epilogue per q-tile: normalize, LEPE, bias, store
    const int H_sp = branch ? 7 : RES;
    const int W_sp = branch ? RES : 7;
    #pragma unroll
    for (int t = 0; t < 2; ++t) if (t < nt) {
        float* ob = &ol[wv][0];
        #pragma unroll
        for (int r = 0; r < 4; ++r) {
            float s = t ? lsum1[r] : lsum0[r];
            s += __shfl_xor(s, 1); s += __shfl_xor(s, 2);
            s += __shfl_xor(s, 4); s += __shfl_xor(s, 8);
            const float inv = 1.f / s;
            const f32x4 Oa = t ? O10 : O00;
            const f32x4 Ob = t ? O11 : O01;
            ob[(g * 4 + r) * 36 + c16]      = Oa[r] * inv;
            ob[(g * 4 + r) * 36 + 16 + c16] = Ob[r] * inv;
        }
        // re-partition: lane -> (row = lane>>2, d-base = (lane&3)*8); same wave, DS in-order
        const int r2 = lane >> 2, db = (lane & 3) * 8;
        const int n0 = (t0 + t) * 16 + r2;
        int i0, j0; nij(n0, branch, i0, j0);
        float acc[8];
        #pragma unroll
        for (int e = 0; e < 8; ++e) acc[e] = ob[r2 * 36 + db + e] + cb[head * 32 + db + e];
        #pragma unroll
        for (int dij = 0; dij < 9; ++dij) {
            const int di = dij / 3 - 1, dj = dij % 3 - 1;
            const int ii = i0 + di, jj = j0 + dj;
            if (ii >= 0 && ii < H_sp && jj >= 0 && jj < W_sp) {
                const float* vp = qkv + qkvB + (long long)((rowBase + ii) * RES + colBase + jj) * C3 + 256 + cbase + db;
                float4 v0 = *(const float4*)vp;
                float4 v1 = *(const float4*)(vp + 4);
                acc[0] += cw[(head * 32 + db + 0) * 9 + dij] * v0.x;
                acc[1] += cw[(head * 32 + db + 1) * 9 + dij] * v0.y;
                acc[2] += cw[(head * 32 + db + 2) * 9 + dij] * v0.z;
                acc[3] += cw[(head * 32 + db + 3) * 9 + dij] * v0.w;
                acc[4] += cw[(head * 32 + db + 4) * 9 + dij] * v1.x;
                acc[5] += cw[(head * 32 + db + 5) * 9 + dij] * v1.y;
                acc[6] += cw[(head * 32 + db + 6) * 9 + dij] * v1.z;
                acc[7] += cw[(head * 32 + db + 7) * 9 + dij] * v1.w;
            }
        }
        const long long Lq = (long long)(rowBase + i0) * RES + colBase + j0;
        float* op = att + ((long long)b * LTOK + Lq) * CDIM + cbase + db;
        *(float4*)op       = make_float4(acc[0], acc[1], acc[2], acc[3]);
        *(float4*)(op + 4) = make_float4(acc[4], acc[5], acc[6], acc[7]);
    }
}

// ---------------- K3: proj + bias + residual ----------------
__global__ __launch_bounds__(128) void k_proj(const float* __restrict__ att,
        const float* __restrict__ wproj, const float* __restrict__ bproj,
        const float* __restrict__ x, float* __restrict__ xmid)
{
    __shared__ float as_[8][128];
    const int tid = threadIdx.x;
    const long long row0 = (long long)blockIdx.x * 8;
    const float4* ag = (const float4*)(att + row0 * CDIM);
    float4* as4 = (float4*)&as_[0][0];
    for (int i = tid; i < 256; i += 128) as4[i] = ag[i];
    __syncthreads();

    const float4* wr = (const float4*)(wproj + (long long)tid * CDIM);
    float acc[8];
    #pragma unroll
    for (int rr = 0; rr < 8; ++rr) acc[rr] = 0.f;
    #pragma unroll 8
    for (int dc = 0; dc < 32; ++dc) {
        float4 w4 = wr[dc];
        #pragma unroll
        for (int rr = 0; rr < 8; ++rr) {
            const float* ip = &as_[rr][dc * 4];
            acc[rr] += w4.x * ip[0] + w4.y * ip[1] + w4.z * ip[2] + w4.w * ip[3];
        }
    }
    const float bb = bproj[tid];
    #pragma unroll
    for (int rr = 0; rr < 8; ++rr)
        xmid[(row0 + rr) * CDIM + tid] = x[(row0 + rr) * CDIM + tid] + acc[rr] + bb;
}

// ---------------- K4: LN2 + FC1 + GELU + FC2 + residual ----------------
__global__ __launch_bounds__(128) void k_mlp(const float* __restrict__ xmid,
        const float* __restrict__ g2, const float* __restrict__ b2,
        const float* __restrict__ wfc1, const float* __restrict__ bfc1,
        const float* __restrict__ wfc2, const float* __restrict__ bfc2,
        float* __restrict__ out)
{
    __shared__ float xs[8][128];
    __shared__ float ys[8][128];
    __shared__ float hs[8][512];
    const int tid = threadIdx.x;
    const long long row0 = (long long)blockIdx.x * 8;

    const float4* xg = (const float4*)(xmid + row0 * CDIM);
    float4* xs4 = (float4*)&xs[0][0];
    for (int i = tid; i < 256; i += 128) xs4[i] = xg[i];
    __syncthreads();

    const int r = tid >> 4, l16 = tid & 15;
    float s = 0.f, s2 = 0.f;
    #pragma unroll
    for (int cc = 0; cc < 8; ++cc) {
        float v = xs[r][l16 * 8 + cc];
        s += v; s2 += v * v;
    }
    #pragma unroll
    for (int m = 8; m >= 1; m >>= 1) { s += __shfl_xor(s, m, 16); s2 += __shfl_xor(s2, m, 16); }
    const float mean = s * (1.f / 128.f);
    const float var = s2 * (1.f / 128.f) - mean * mean;
    const float rs = rsqrtf(var + 1e-5f);
    #pragma unroll
    for (int cc = 0; cc < 8; ++cc) {
        int c = l16 * 8 + cc;
        ys[r][c] = (xs[r][c] - mean) * rs * g2[c] + b2[c];
    }
    __syncthreads();

    for (int p = 0; p < 4; ++p) {
        const int j = tid + (p << 7);
        const float4* wr = (const float4*)(wfc1 + (long long)j * CDIM);
        float acc[8];
        const float bj = bfc1[j];
        #pragma unroll
        for (int rr = 0; rr < 8; ++rr) acc[rr] = bj;
        #pragma unroll 8
        for (int dc = 0; dc < 32; ++dc) {
            float4 w4 = wr[dc];
            #pragma unroll
            for (int rr = 0; rr < 8; ++rr) {
                const float* ip = &ys[rr][dc * 4];
                acc[rr] += w4.x * ip[0] + w4.y * ip[1] + w4.z * ip[2] + w4.w * ip[3];
            }
        }
        #pragma unroll
        for (int rr = 0; rr < 8; ++rr) {
            float a = acc[rr];
            hs[rr][j] = 0.5f * a * (1.0f + erff(a * 0.70710678118654752f));
        }
    }
    __syncthreads();

    const float4* wr2 = (const float4*)(wfc2 + (long long)tid * 512);
    float acc2[8];
    const float bc = bfc2[tid];
    #pragma unroll
    for (int rr = 0; rr < 8; ++rr) acc2[rr] = bc + xs[rr][tid];
    #pragma unroll 8
    for (int dc = 0; dc < 128; ++dc) {
        float4 w4 = wr2[dc];
        #pragma unroll
        for (int rr = 0; rr < 8; ++rr) {
            const float* ip = &hs[rr][dc * 4];
            acc2[rr] += w4.x * ip[0] + w4.y * ip[1] + w4.z * ip[2] + w4.w * ip[3];
        }
    }
    #pragma unroll
    for (int rr = 0; rr < 8; ++rr)
        out[(row0 + rr) * CDIM + tid] = acc2[rr];
}

extern "C" void kernel_launch(void* const* d_in, const int* in_sizes, int n_in,
                              void* d_out, int out_size, void* d_ws, size_t ws_size,
                              hipStream_t stream) {
    const float* x     = (const float*)d_in[0];
    const float* g1    = (const float*)d_in[1];
    const float* b1    = (const float*)d_in[2];
    const float* wqkv  = (const float*)d_in[3];
    const float* cw0   = (const float*)d_in[4];
    const float* cb0   = (const float*)d_in[5];
    const float* cw1   = (const float*)d_in[6];
    const float* cb1   = (const float*)d_in[7];
    const float* wproj = (const float*)d_in[8];
    const float* bproj = (const float*)d_in[9];
    const float* g2    = (const float*)d_in[10];
    const float* b2    = (const float*)d_in[11];
    const float* wfc1  = (const float*)d_in[12];
    const float* bfc1  = (const float*)d_in[13];
    const float* wfc2  = (const float*)d_in[14];
    const float* bfc2  = (const float*)d_in[15];

    float* ws   = (float*)d_ws;
    float* qkv  = ws;                       // 25088*384 floats
    float* att  = qkv + (size_t)NROWS * C3;
    float* xmid = att + (size_t)NROWS * CDIM;

    float* out = (float*)d_out;

    k_ln_qkv<<<NROWS / 8, 128, 0, stream>>>(x, g1, b1, wqkv, qkv);
    k_attn_mfma<<<dim3(128, 7), 256, 0, stream>>>(qkv, cw0, cb0, cw1, cb1, att);
    k_proj<<<NROWS / 8, 128, 0, stream>>>(att, wproj, bproj, x, xmid);
    k_mlp<<<NROWS / 8, 128, 0, stream>>>(xmid, g2, b2, wfc1, bfc1, wfc2, bfc2, out);
}

// Round 3
// 145.994 us; speedup vs baseline: 4.2944x; 2.6807x over previous
//
#include <hip/hip_runtime.h>
#include <cstdint>

#define LTOK 12544
#define BATCH 2
#define CDIM 128
#define C3 384
#define RES 112
#define NROWS (BATCH * LTOK)  // 25088
#define SCALE 0.17677669529663687f  // 1/sqrt(32)

typedef __attribute__((ext_vector_type(8))) short bf16x8;
typedef __attribute__((ext_vector_type(4))) float f32x4;

__device__ inline ushort f2b(float f) {
    union { float f; unsigned u; } v; v.f = f;
    unsigned r = (v.u + 0x7FFFu + ((v.u >> 16) & 1u)) >> 16;
    return (ushort)r;
}
__device__ inline float b2f(ushort u) {
    union { float f; unsigned u; } v; v.u = ((unsigned)u) << 16; return v.f;
}

// map window-local token n -> (i, j); branch 0: W_sp=7, branch 1: W_sp=112
__device__ inline void nij(int n, int branch, int& i, int& j) {
    if (branch == 0) { i = n / 7; j = n - i * 7; }
    else             { i = n / 112; j = n - i * 112; }
}

// ---------------- K0: convert all weights to bf16 (196608 floats = 49152 vec4) ----------------
__global__ __launch_bounds__(256) void k_cvt(const float* __restrict__ w0, const float* __restrict__ w1,
        const float* __restrict__ w2, const float* __restrict__ w3,
        ushort* __restrict__ o0, ushort* __restrict__ o1,
        ushort* __restrict__ o2, ushort* __restrict__ o3)
{
    int idx = blockIdx.x * 256 + threadIdx.x;  // vec4 index
    const float* src; ushort* dst; int vi;
    if      (idx < 12288) { src = w0; dst = o0; vi = idx; }
    else if (idx < 16384) { src = w1; dst = o1; vi = idx - 12288; }
    else if (idx < 32768) { src = w2; dst = o2; vi = idx - 16384; }
    else                  { src = w3; dst = o3; vi = idx - 32768; }
    float4 v = ((const float4*)src)[vi];
    ushort4 r; r.x = f2b(v.x); r.y = f2b(v.y); r.z = f2b(v.z); r.w = f2b(v.w);
    ((ushort4*)dst)[vi] = r;
}

// ---------------- K1: LN1 + QKV GEMM via MFMA (16 rows / 256-thread block) ----------------
__global__ __launch_bounds__(256) void k_ln_qkv(const float* __restrict__ x,
        const float* __restrict__ g1, const float* __restrict__ b1,
        const ushort* __restrict__ wqkv_bf, ushort* __restrict__ qkv)
{
    __shared__ ushort ys[16][136];
    const int tid = threadIdx.x;
    const long long row0 = (long long)blockIdx.x * 16;

    // LN: 16 threads per row
    {
        const int r = tid >> 4, l16 = tid & 15;
        const float* xr = x + (row0 + r) * CDIM + l16 * 8;
        float4 a0 = *(const float4*)xr;
        float4 a1 = *(const float4*)(xr + 4);
        float s  = a0.x + a0.y + a0.z + a0.w + a1.x + a1.y + a1.z + a1.w;
        float s2 = a0.x*a0.x + a0.y*a0.y + a0.z*a0.z + a0.w*a0.w
                 + a1.x*a1.x + a1.y*a1.y + a1.z*a1.z + a1.w*a1.w;
        #pragma unroll
        for (int m = 8; m >= 1; m >>= 1) { s += __shfl_xor(s, m, 16); s2 += __shfl_xor(s2, m, 16); }
        const float mean = s * (1.f / 128.f);
        const float var = s2 * (1.f / 128.f) - mean * mean;
        const float rs = rsqrtf(var + 1e-5f);
        float4 g0 = *(const float4*)(g1 + l16 * 8);
        float4 g4 = *(const float4*)(g1 + l16 * 8 + 4);
        float4 c0 = *(const float4*)(b1 + l16 * 8);
        float4 c4 = *(const float4*)(b1 + l16 * 8 + 4);
        bf16x8 yy;
        yy[0] = (short)f2b((a0.x - mean) * rs * g0.x + c0.x);
        yy[1] = (short)f2b((a0.y - mean) * rs * g0.y + c0.y);
        yy[2] = (short)f2b((a0.z - mean) * rs * g0.z + c0.z);
        yy[3] = (short)f2b((a0.w - mean) * rs * g0.w + c0.w);
        yy[4] = (short)f2b((a1.x - mean) * rs * g4.x + c4.x);
        yy[5] = (short)f2b((a1.y - mean) * rs * g4.y + c4.y);
        yy[6] = (short)f2b((a1.z - mean) * rs * g4.z + c4.z);
        yy[7] = (short)f2b((a1.w - mean) * rs * g4.w + c4.w);
        *(bf16x8*)&ys[r][l16 * 8] = yy;
    }
    __syncthreads();

    const int wv = tid >> 6, lane = tid & 63;
    const int c16 = lane & 15, g = lane >> 4;
    bf16x8 af[4];
    #pragma unroll
    for (int kc = 0; kc < 4; ++kc) af[kc] = *(const bf16x8*)&ys[c16][kc * 32 + g * 8];

    #pragma unroll
    for (int t = 0; t < 6; ++t) {
        const int n0 = wv * 96 + t * 16;
        f32x4 acc = {0.f, 0.f, 0.f, 0.f};
        #pragma unroll
        for (int kc = 0; kc < 4; ++kc) {
            bf16x8 bf = *(const bf16x8*)&wqkv_bf[(n0 + c16) * CDIM + kc * 32 + g * 8];
            acc = __builtin_amdgcn_mfma_f32_16x16x32_bf16(af[kc], bf, acc, 0, 0, 0);
        }
        #pragma unroll
        for (int r = 0; r < 4; ++r)
            qkv[(row0 + g * 4 + r) * C3 + n0 + c16] = f2b(acc[r]);
    }
}

// ---------------- K2: windowed attention + LEPE via bf16 MFMA ----------------
__global__ __launch_bounds__(256) void k_attn_mfma(const ushort* __restrict__ qkv,
        const float* __restrict__ cw0, const float* __restrict__ cb0,
        const float* __restrict__ cw1, const float* __restrict__ cb1,
        ushort* __restrict__ att)
{
    __shared__ __align__(16) ushort ks[112 * 40];
    __shared__ __align__(16) ushort vt[32 * 136];
    __shared__ __align__(16) ushort pl[4][16 * 40];
    __shared__ __align__(16) float  ol[4][16 * 36];

    const int tid = threadIdx.x;
    const int wv = tid >> 6, lane = tid & 63;
    const int g = lane >> 4, c16 = lane & 15;

    const int wh = blockIdx.x;
    const int branch = wh >> 6;
    const int idx = wh & 63;
    const int win = idx >> 1, head = idx & 1;
    const int b = win >> 4, w = win & 15;
    const int rowBase = branch ? w * 7 : 0;
    const int colBase = branch ? 0 : w * 7;
    const float* cw = branch ? cw1 : cw0;
    const float* cb = branch ? cb1 : cb0;
    const int cbase = branch * 64 + head * 32;
    const long long qkvB = (long long)b * LTOK * C3;

    {
        const int row = tid >> 3, cwd = tid & 7;
        *(unsigned*)&vt[row * 136 + 112 + cwd * 2] = 0u;
    }

    const int t0 = blockIdx.y * 7 + 2 * wv;
    const int nt = (2 * wv + 1 < 7) ? 2 : 1;

    bf16x8 qf[2];
    #pragma unroll
    for (int t = 0; t < 2; ++t) if (t < nt) {
        int n = (t0 + t) * 16 + c16;
        int i, j; nij(n, branch, i, j);
        const ushort* qp = qkv + qkvB + (long long)((rowBase + i) * RES + colBase + j) * C3 + cbase + g * 8;
        bf16x8 qq = *(const bf16x8*)qp;
        #pragma unroll
        for (int e = 0; e < 8; ++e) qq[e] = (short)f2b(b2f((ushort)qq[e]) * SCALE);
        qf[t] = qq;
    }

    f32x4 O00 = {0.f,0.f,0.f,0.f}, O01 = {0.f,0.f,0.f,0.f};
    f32x4 O10 = {0.f,0.f,0.f,0.f}, O11 = {0.f,0.f,0.f,0.f};
    float lsum0[4] = {0.f,0.f,0.f,0.f};
    float lsum1[4] = {0.f,0.f,0.f,0.f};

    for (int cc = 0; cc < 7; ++cc) {
        __syncthreads();
        for (int u = tid; u < 448; u += 256) {
            const int key = u >> 2, d8 = (u & 3) * 8;
            const int n = cc * 112 + key;
            int i, j; nij(n, branch, i, j);
            const ushort* base = qkv + qkvB + (long long)((rowBase + i) * RES + colBase + j) * C3 + cbase + d8;
            bf16x8 kk = *(const bf16x8*)(base + 128);
            bf16x8 vv = *(const bf16x8*)(base + 256);
            *(bf16x8*)&ks[key * 40 + d8] = kk;
            #pragma unroll
            for (int e = 0; e < 8; ++e) vt[(d8 + e) * 136 + key] = (ushort)vv[e];
        }
        __syncthreads();

        #pragma unroll
        for (int p = 0; p < 4; ++p) {
            bf16x8 kf0 = *(const bf16x8*)&ks[(p * 32 + c16) * 40 + g * 8];
            bf16x8 kf1;
            if (p < 3) kf1 = *(const bf16x8*)&ks[(p * 32 + 16 + c16) * 40 + g * 8];
            bf16x8 vf0 = *(const bf16x8*)&vt[c16 * 136 + p * 32 + g * 8];
            bf16x8 vf1 = *(const bf16x8*)&vt[(16 + c16) * 136 + p * 32 + g * 8];
            ushort* pb = &pl[wv][0];

            #pragma unroll
            for (int t = 0; t < 2; ++t) if (t < nt) {
                const bf16x8 qq = t ? qf[1] : qf[0];
                f32x4 z = {0.f,0.f,0.f,0.f};
                f32x4 S0 = __builtin_amdgcn_mfma_f32_16x16x32_bf16(qq, kf0, z, 0, 0, 0);
                f32x4 S1 = z;
                if (p < 3) S1 = __builtin_amdgcn_mfma_f32_16x16x32_bf16(qq, kf1, z, 0, 0, 0);
                ushort pw0[4], pw1[4];
                #pragma unroll
                for (int r = 0; r < 4; ++r) {
                    float e0 = __expf(S0[r]);
                    if (t) lsum1[r] += e0; else lsum0[r] += e0;
                    pw0[r] = f2b(e0);
                    if (p < 3) {
                        float e1 = __expf(S1[r]);
                        if (t) lsum1[r] += e1; else lsum0[r] += e1;
                        pw1[r] = f2b(e1);
                    } else pw1[r] = 0;
                }
                #pragma unroll
                for (int r = 0; r < 4; ++r) {
                    pb[(g * 4 + r) * 40 + c16]      = pw0[r];
                    pb[(g * 4 + r) * 40 + 16 + c16] = pw1[r];
                }
                bf16x8 pf = *(const bf16x8*)&pb[c16 * 40 + g * 8];
                if (t) {
                    O10 = __builtin_amdgcn_mfma_f32_16x16x32_bf16(pf, vf0, O10, 0, 0, 0);
                    O11 = __builtin_amdgcn_mfma_f32_16x16x32_bf16(pf, vf1, O11, 0, 0, 0);
                } else {
                    O00 = __builtin_amdgcn_mfma_f32_16x16x32_bf16(pf, vf0, O00, 0, 0, 0);
                    O01 = __builtin_amdgcn_mfma_f32_16x16x32_bf16(pf, vf1, O01, 0, 0, 0);
                }
            }
        }
    }

    const int H_sp = branch ? 7 : RES;
    const int W_sp = branch ? RES : 7;
    #pragma unroll
    for (int t = 0; t < 2; ++t) if (t < nt) {
        float* ob = &ol[wv][0];
        #pragma unroll
        for (int r = 0; r < 4; ++r) {
            float s = t ? lsum1[r] : lsum0[r];
            s += __shfl_xor(s, 1); s += __shfl_xor(s, 2);
            s += __shfl_xor(s, 4); s += __shfl_xor(s, 8);
            const float inv = 1.f / s;
            const f32x4 Oa = t ? O10 : O00;
            const f32x4 Ob = t ? O11 : O01;
            ob[(g * 4 + r) * 36 + c16]      = Oa[r] * inv;
            ob[(g * 4 + r) * 36 + 16 + c16] = Ob[r] * inv;
        }
        const int r2 = lane >> 2, db = (lane & 3) * 8;
        const int n0 = (t0 + t) * 16 + r2;
        int i0, j0; nij(n0, branch, i0, j0);
        float acc[8];
        #pragma unroll
        for (int e = 0; e < 8; ++e) acc[e] = ob[r2 * 36 + db + e] + cb[head * 32 + db + e];
        #pragma unroll
        for (int dij = 0; dij < 9; ++dij) {
            const int di = dij / 3 - 1, dj = dij % 3 - 1;
            const int ii = i0 + di, jj = j0 + dj;
            if (ii >= 0 && ii < H_sp && jj >= 0 && jj < W_sp) {
                const ushort* vp = qkv + qkvB + (long long)((rowBase + ii) * RES + colBase + jj) * C3 + 256 + cbase + db;
                bf16x8 vv = *(const bf16x8*)vp;
                #pragma unroll
                for (int e = 0; e < 8; ++e)
                    acc[e] += cw[(head * 32 + db + e) * 9 + dij] * b2f((ushort)vv[e]);
            }
        }
        const long long Lq = (long long)(rowBase + i0) * RES + colBase + j0;
        ushort* op = att + ((long long)b * LTOK + Lq) * CDIM + cbase + db;
        bf16x8 ov;
        #pragma unroll
        for (int e = 0; e < 8; ++e) ov[e] = (short)f2b(acc[e]);
        *(bf16x8*)op = ov;
    }
}

// ---------------- K3: proj + bias + residual via MFMA (16 rows / block) ----------------
__global__ __launch_bounds__(256) void k_proj(const ushort* __restrict__ att,
        const ushort* __restrict__ wproj_bf, const float* __restrict__ bproj,
        const float* __restrict__ x, float* __restrict__ xmid)
{
    const int tid = threadIdx.x;
    const int wv = tid >> 6, lane = tid & 63;
    const int c16 = lane & 15, g = lane >> 4;
    const long long row0 = (long long)blockIdx.x * 16;

    bf16x8 af[4];
    #pragma unroll
    for (int kc = 0; kc < 4; ++kc)
        af[kc] = *(const bf16x8*)&att[(row0 + c16) * CDIM + kc * 32 + g * 8];

    #pragma unroll
    for (int t = 0; t < 2; ++t) {
        const int n0 = wv * 32 + t * 16;
        f32x4 acc = {0.f, 0.f, 0.f, 0.f};
        #pragma unroll
        for (int kc = 0; kc < 4; ++kc) {
            bf16x8 bf = *(const bf16x8*)&wproj_bf[(n0 + c16) * CDIM + kc * 32 + g * 8];
            acc = __builtin_amdgcn_mfma_f32_16x16x32_bf16(af[kc], bf, acc, 0, 0, 0);
        }
        const int col = n0 + c16;
        const float bb = bproj[col];
        #pragma unroll
        for (int r = 0; r < 4; ++r) {
            const long long row = row0 + g * 4 + r;
            xmid[row * CDIM + col] = acc[r] + x[row * CDIM + col] + bb;
        }
    }
}

// ---------------- K4: LN2 + FC1 + GELU + FC2 + residual via MFMA (16 rows / block) ----------------
__global__ __launch_bounds__(256) void k_mlp(const float* __restrict__ xmid,
        const float* __restrict__ g2, const float* __restrict__ b2,
        const ushort* __restrict__ w1bf, const float* __restrict__ bfc1,
        const ushort* __restrict__ w2bf, const float* __restrict__ bfc2,
        float* __restrict__ out)
{
    __shared__ float  xs[16][132];
    __shared__ ushort ys[16][136];
    __shared__ ushort hs[16][520];
    const int tid = threadIdx.x;
    const long long row0 = (long long)blockIdx.x * 16;

    {
        const int r = tid >> 4, l16 = tid & 15;
        const float* xr = xmid + (row0 + r) * CDIM + l16 * 8;
        float4 a0 = *(const float4*)xr;
        float4 a1 = *(const float4*)(xr + 4);
        *(float4*)&xs[r][l16 * 8]     = a0;
        *(float4*)&xs[r][l16 * 8 + 4] = a1;
        float s  = a0.x + a0.y + a0.z + a0.w + a1.x + a1.y + a1.z + a1.w;
        float s2 = a0.x*a0.x + a0.y*a0.y + a0.z*a0.z + a0.w*a0.w
                 + a1.x*a1.x + a1.y*a1.y + a1.z*a1.z + a1.w*a1.w;
        #pragma unroll
        for (int m = 8; m >= 1; m >>= 1) { s += __shfl_xor(s, m, 16); s2 += __shfl_xor(s2, m, 16); }
        const float mean = s * (1.f / 128.f);
        const float var = s2 * (1.f / 128.f) - mean * mean;
        const float rs = rsqrtf(var + 1e-5f);
        float4 g0 = *(const float4*)(g2 + l16 * 8);
        float4 g4 = *(const float4*)(g2 + l16 * 8 + 4);
        float4 c0 = *(const float4*)(b2 + l16 * 8);
        float4 c4 = *(const float4*)(b2 + l16 * 8 + 4);
        bf16x8 yy;
        yy[0] = (short)f2b((a0.x - mean) * rs * g0.x + c0.x);
        yy[1] = (short)f2b((a0.y - mean) * rs * g0.y + c0.y);
        yy[2] = (short)f2b((a0.z - mean) * rs * g0.z + c0.z);
        yy[3] = (short)f2b((a0.w - mean) * rs * g0.w + c0.w);
        yy[4] = (short)f2b((a1.x - mean) * rs * g4.x + c4.x);
        yy[5] = (short)f2b((a1.y - mean) * rs * g4.y + c4.y);
        yy[6] = (short)f2b((a1.z - mean) * rs * g4.z + c4.z);
        yy[7] = (short)f2b((a1.w - mean) * rs * g4.w + c4.w);
        *(bf16x8*)&ys[r][l16 * 8] = yy;
    }
    __syncthreads();

    const int wv = tid >> 6, lane = tid & 63;
    const int c16 = lane & 15, g = lane >> 4;

    bf16x8 af[4];
    #pragma unroll
    for (int kc = 0; kc < 4; ++kc) af[kc] = *(const bf16x8*)&ys[c16][kc * 32 + g * 8];

    // FC1 + GELU -> hs (bf16)
    #pragma unroll
    for (int t = 0; t < 8; ++t) {
        const int n0 = wv * 128 + t * 16;
        f32x4 acc = {0.f, 0.f, 0.f, 0.f};
        #pragma unroll
        for (int kc = 0; kc < 4; ++kc) {
            bf16x8 bf = *(const bf16x8*)&w1bf[(n0 + c16) * CDIM + kc * 32 + g * 8];
            acc = __builtin_amdgcn_mfma_f32_16x16x32_bf16(af[kc], bf, acc, 0, 0, 0);
        }
        const int col = n0 + c16;
        const float bj = bfc1[col];
        #pragma unroll
        for (int r = 0; r < 4; ++r) {
            float a = acc[r] + bj;
            float ge = 0.5f * a * (1.0f + erff(a * 0.70710678118654752f));
            hs[g * 4 + r][col] = f2b(ge);
        }
    }
    __syncthreads();

    // FC2 + residual
    bf16x8 ah[16];
    #pragma unroll
    for (int kc = 0; kc < 16; ++kc) ah[kc] = *(const bf16x8*)&hs[c16][kc * 32 + g * 8];

    #pragma unroll
    for (int t = 0; t < 2; ++t) {
        const int n0 = wv * 32 + t * 16;
        f32x4 acc = {0.f, 0.f, 0.f, 0.f};
        #pragma unroll
        for (int kc = 0; kc < 16; ++kc) {
            bf16x8 bf = *(const bf16x8*)&w2bf[(n0 + c16) * 512 + kc * 32 + g * 8];
            acc = __builtin_amdgcn_mfma_f32_16x16x32_bf16(ah[kc], bf, acc, 0, 0, 0);
        }
        const int col = n0 + c16;
        const float bb = bfc2[col];
        #pragma unroll
        for (int r = 0; r < 4; ++r)
            out[(row0 + g * 4 + r) * CDIM + col] = acc[r] + bb + xs[g * 4 + r][col];
    }
}

extern "C" void kernel_launch(void* const* d_in, const int* in_sizes, int n_in,
                              void* d_out, int out_size, void* d_ws, size_t ws_size,
                              hipStream_t stream) {
    const float* x     = (const float*)d_in[0];
    const float* g1    = (const float*)d_in[1];
    const float* b1    = (const float*)d_in[2];
    const float* wqkv  = (const float*)d_in[3];
    const float* cw0   = (const float*)d_in[4];
    const float* cb0   = (const float*)d_in[5];
    const float* cw1   = (const float*)d_in[6];
    const float* cb1   = (const float*)d_in[7];
    const float* wproj = (const float*)d_in[8];
    const float* bproj = (const float*)d_in[9];
    const float* g2    = (const float*)d_in[10];
    const float* b2    = (const float*)d_in[11];
    const float* wfc1  = (const float*)d_in[12];
    const float* bfc1  = (const float*)d_in[13];
    const float* wfc2  = (const float*)d_in[14];
    const float* bfc2  = (const float*)d_in[15];

    char* wsb = (char*)d_ws;
    ushort* qkv_bf   = (ushort*)wsb;                           // 25088*384*2 = 19,267,584 B
    ushort* att_bf   = (ushort*)(wsb + 19267584);              //  6,422,528 B
    float*  xmid     = (float*) (wsb + 19267584 + 6422528);    // 12,845,056 B
    char*   wbase    = wsb + 38535168;
    ushort* wqkv_bf  = (ushort*)(wbase);                       // 98,304 B
    ushort* wproj_bf = (ushort*)(wbase + 98304);               // 32,768 B
    ushort* wfc1_bf  = (ushort*)(wbase + 98304 + 32768);       // 131,072 B
    ushort* wfc2_bf  = (ushort*)(wbase + 98304 + 32768 + 131072);

    float* out = (float*)d_out;

    k_cvt<<<192, 256, 0, stream>>>(wqkv, wproj, wfc1, wfc2, wqkv_bf, wproj_bf, wfc1_bf, wfc2_bf);
    k_ln_qkv<<<NROWS / 16, 256, 0, stream>>>(x, g1, b1, wqkv_bf, qkv_bf);
    k_attn_mfma<<<dim3(128, 7), 256, 0, stream>>>(qkv_bf, cw0, cb0, cw1, cb1, att_bf);
    k_proj<<<NROWS / 16, 256, 0, stream>>>(att_bf, wproj_bf, bproj, x, xmid);
    k_mlp<<<NROWS / 16, 256, 0, stream>>>(xmid, g2, b2, wfc1_bf, bfc1, wfc2_bf, bfc2, out);
}

// Round 4
// 126.180 us; speedup vs baseline: 4.9688x; 1.1570x over previous
//
#include <hip/hip_runtime.h>
#include <cstdint>

#define LTOK 12544
#define BATCH 2
#define CDIM 128
#define C3 384
#define RES 112
#define NROWS (BATCH * LTOK)  // 25088
#define SCALE 0.17677669529663687f  // 1/sqrt(32)

typedef __attribute__((ext_vector_type(8))) short bf16x8;
typedef __attribute__((ext_vector_type(4))) float f32x4;

__device__ inline ushort f2b(float f) {
    union { float f; unsigned u; } v; v.f = f;
    unsigned r = (v.u + 0x7FFFu + ((v.u >> 16) & 1u)) >> 16;
    return (ushort)r;
}
__device__ inline float b2f(ushort u) {
    union { float f; unsigned u; } v; v.u = ((unsigned)u) << 16; return v.f;
}
__device__ inline float gelu_f(float a) {
    return 0.5f * a * (1.0f + erff(a * 0.70710678118654752f));
}

// map window-local token n -> (i, j); branch 0: W_sp=7, branch 1: W_sp=112
__device__ inline void nij(int n, int branch, int& i, int& j) {
    if (branch == 0) { i = n / 7; j = n - i * 7; }
    else             { i = n / 112; j = n - i * 112; }
}

// ---------------- K0: convert all weights to bf16 ----------------
__global__ __launch_bounds__(256) void k_cvt(const float* __restrict__ w0, const float* __restrict__ w1,
        const float* __restrict__ w2, const float* __restrict__ w3,
        ushort* __restrict__ o0, ushort* __restrict__ o1,
        ushort* __restrict__ o2, ushort* __restrict__ o3)
{
    int idx = blockIdx.x * 256 + threadIdx.x;  // vec4 index
    const float* src; ushort* dst; int vi;
    if      (idx < 12288) { src = w0; dst = o0; vi = idx; }
    else if (idx < 16384) { src = w1; dst = o1; vi = idx - 12288; }
    else if (idx < 32768) { src = w2; dst = o2; vi = idx - 16384; }
    else                  { src = w3; dst = o3; vi = idx - 32768; }
    float4 v = ((const float4*)src)[vi];
    ushort4 r; r.x = f2b(v.x); r.y = f2b(v.y); r.z = f2b(v.z); r.w = f2b(v.w);
    ((ushort4*)dst)[vi] = r;
}

// ---------------- K1: LN1 + QKV GEMM via MFMA (32 rows / 256-thread block) ----------------
// swapped operands: D col = m-row, D row = n-col -> 8B coalesced qkv stores
__global__ __launch_bounds__(256) void k_ln_qkv(const float* __restrict__ x,
        const float* __restrict__ g1, const float* __restrict__ b1,
        const ushort* __restrict__ wqkv_bf, ushort* __restrict__ qkv)
{
    __shared__ ushort ys[32][136];
    const int tid = threadIdx.x;
    const long long row0 = (long long)blockIdx.x * 32;

    // LN: 8 threads per row, 16 elems each
    {
        const int r = tid >> 3, l8 = tid & 7;
        const float* xr = x + (row0 + r) * CDIM + l8 * 16;
        float4 a[4];
        #pragma unroll
        for (int i = 0; i < 4; ++i) a[i] = ((const float4*)xr)[i];
        float s = 0.f, s2 = 0.f;
        #pragma unroll
        for (int i = 0; i < 4; ++i) {
            s  += a[i].x + a[i].y + a[i].z + a[i].w;
            s2 += a[i].x*a[i].x + a[i].y*a[i].y + a[i].z*a[i].z + a[i].w*a[i].w;
        }
        #pragma unroll
        for (int m = 4; m >= 1; m >>= 1) { s += __shfl_xor(s, m, 8); s2 += __shfl_xor(s2, m, 8); }
        const float mean = s * (1.f / 128.f);
        const float var = s2 * (1.f / 128.f) - mean * mean;
        const float rs = rsqrtf(var + 1e-5f);
        ushort4 w[4];
        #pragma unroll
        for (int i = 0; i < 4; ++i) {
            float4 gg = *(const float4*)(g1 + l8 * 16 + i * 4);
            float4 bb = *(const float4*)(b1 + l8 * 16 + i * 4);
            w[i].x = f2b((a[i].x - mean) * rs * gg.x + bb.x);
            w[i].y = f2b((a[i].y - mean) * rs * gg.y + bb.y);
            w[i].z = f2b((a[i].z - mean) * rs * gg.z + bb.z);
            w[i].w = f2b((a[i].w - mean) * rs * gg.w + bb.w);
        }
        #pragma unroll
        for (int i = 0; i < 4; ++i) *(ushort4*)&ys[r][l8 * 16 + i * 4] = w[i];
    }
    __syncthreads();

    const int wv = tid >> 6, lane = tid & 63;
    const int c16 = lane & 15, g = lane >> 4;

    bf16x8 yb[2][4];
    #pragma unroll
    for (int mt = 0; mt < 2; ++mt)
        #pragma unroll
        for (int kc = 0; kc < 4; ++kc)
            yb[mt][kc] = *(const bf16x8*)&ys[mt * 16 + c16][kc * 32 + g * 8];

    #pragma unroll
    for (int t = 0; t < 6; ++t) {
        const int n0 = wv * 96 + t * 16;
        bf16x8 aw[4];
        #pragma unroll
        for (int kc = 0; kc < 4; ++kc)
            aw[kc] = *(const bf16x8*)&wqkv_bf[(n0 + c16) * CDIM + kc * 32 + g * 8];
        #pragma unroll
        for (int mt = 0; mt < 2; ++mt) {
            f32x4 acc = {0.f, 0.f, 0.f, 0.f};
            #pragma unroll
            for (int kc = 0; kc < 4; ++kc)
                acc = __builtin_amdgcn_mfma_f32_16x16x32_bf16(aw[kc], yb[mt][kc], acc, 0, 0, 0);
            ushort4 sv;
            sv.x = f2b(acc[0]); sv.y = f2b(acc[1]); sv.z = f2b(acc[2]); sv.w = f2b(acc[3]);
            *(ushort4*)&qkv[(row0 + mt * 16 + c16) * C3 + n0 + g * 4] = sv;
        }
    }
}

// ---------------- K2: windowed attention + LEPE via bf16 MFMA (unchanged) ----------------
__global__ __launch_bounds__(256) void k_attn_mfma(const ushort* __restrict__ qkv,
        const float* __restrict__ cw0, const float* __restrict__ cb0,
        const float* __restrict__ cw1, const float* __restrict__ cb1,
        ushort* __restrict__ att)
{
    __shared__ __align__(16) ushort ks[112 * 40];
    __shared__ __align__(16) ushort vt[32 * 136];
    __shared__ __align__(16) ushort pl[4][16 * 40];
    __shared__ __align__(16) float  ol[4][16 * 36];

    const int tid = threadIdx.x;
    const int wv = tid >> 6, lane = tid & 63;
    const int g = lane >> 4, c16 = lane & 15;

    const int wh = blockIdx.x;
    const int branch = wh >> 6;
    const int idx = wh & 63;
    const int win = idx >> 1, head = idx & 1;
    const int b = win >> 4, w = win & 15;
    const int rowBase = branch ? w * 7 : 0;
    const int colBase = branch ? 0 : w * 7;
    const float* cw = branch ? cw1 : cw0;
    const float* cb = branch ? cb1 : cb0;
    const int cbase = branch * 64 + head * 32;
    const long long qkvB = (long long)b * LTOK * C3;

    {
        const int row = tid >> 3, cwd = tid & 7;
        *(unsigned*)&vt[row * 136 + 112 + cwd * 2] = 0u;
    }

    const int t0 = blockIdx.y * 7 + 2 * wv;
    const int nt = (2 * wv + 1 < 7) ? 2 : 1;

    bf16x8 qf[2];
    #pragma unroll
    for (int t = 0; t < 2; ++t) if (t < nt) {
        int n = (t0 + t) * 16 + c16;
        int i, j; nij(n, branch, i, j);
        const ushort* qp = qkv + qkvB + (long long)((rowBase + i) * RES + colBase + j) * C3 + cbase + g * 8;
        bf16x8 qq = *(const bf16x8*)qp;
        #pragma unroll
        for (int e = 0; e < 8; ++e) qq[e] = (short)f2b(b2f((ushort)qq[e]) * SCALE);
        qf[t] = qq;
    }

    f32x4 O00 = {0.f,0.f,0.f,0.f}, O01 = {0.f,0.f,0.f,0.f};
    f32x4 O10 = {0.f,0.f,0.f,0.f}, O11 = {0.f,0.f,0.f,0.f};
    float lsum0[4] = {0.f,0.f,0.f,0.f};
    float lsum1[4] = {0.f,0.f,0.f,0.f};

    for (int cc = 0; cc < 7; ++cc) {
        __syncthreads();
        for (int u = tid; u < 448; u += 256) {
            const int key = u >> 2, d8 = (u & 3) * 8;
            const int n = cc * 112 + key;
            int i, j; nij(n, branch, i, j);
            const ushort* base = qkv + qkvB + (long long)((rowBase + i) * RES + colBase + j) * C3 + cbase + d8;
            bf16x8 kk = *(const bf16x8*)(base + 128);
            bf16x8 vv = *(const bf16x8*)(base + 256);
            *(bf16x8*)&ks[key * 40 + d8] = kk;
            #pragma unroll
            for (int e = 0; e < 8; ++e) vt[(d8 + e) * 136 + key] = (ushort)vv[e];
        }
        __syncthreads();

        #pragma unroll
        for (int p = 0; p < 4; ++p) {
            bf16x8 kf0 = *(const bf16x8*)&ks[(p * 32 + c16) * 40 + g * 8];
            bf16x8 kf1;
            if (p < 3) kf1 = *(const bf16x8*)&ks[(p * 32 + 16 + c16) * 40 + g * 8];
            bf16x8 vf0 = *(const bf16x8*)&vt[c16 * 136 + p * 32 + g * 8];
            bf16x8 vf1 = *(const bf16x8*)&vt[(16 + c16) * 136 + p * 32 + g * 8];
            ushort* pb = &pl[wv][0];

            #pragma unroll
            for (int t = 0; t < 2; ++t) if (t < nt) {
                const bf16x8 qq = t ? qf[1] : qf[0];
                f32x4 z = {0.f,0.f,0.f,0.f};
                f32x4 S0 = __builtin_amdgcn_mfma_f32_16x16x32_bf16(qq, kf0, z, 0, 0, 0);
                f32x4 S1 = z;
                if (p < 3) S1 = __builtin_amdgcn_mfma_f32_16x16x32_bf16(qq, kf1, z, 0, 0, 0);
                ushort pw0[4], pw1[4];
                #pragma unroll
                for (int r = 0; r < 4; ++r) {
                    float e0 = __expf(S0[r]);
                    if (t) lsum1[r] += e0; else lsum0[r] += e0;
                    pw0[r] = f2b(e0);
                    if (p < 3) {
                        float e1 = __expf(S1[r]);
                        if (t) lsum1[r] += e1; else lsum0[r] += e1;
                        pw1[r] = f2b(e1);
                    } else pw1[r] = 0;
                }
                #pragma unroll
                for (int r = 0; r < 4; ++r) {
                    pb[(g * 4 + r) * 40 + c16]      = pw0[r];
                    pb[(g * 4 + r) * 40 + 16 + c16] = pw1[r];
                }
                bf16x8 pf = *(const bf16x8*)&pb[c16 * 40 + g * 8];
                if (t) {
                    O10 = __builtin_amdgcn_mfma_f32_16x16x32_bf16(pf, vf0, O10, 0, 0, 0);
                    O11 = __builtin_amdgcn_mfma_f32_16x16x32_bf16(pf, vf1, O11, 0, 0, 0);
                } else {
                    O00 = __builtin_amdgcn_mfma_f32_16x16x32_bf16(pf, vf0, O00, 0, 0, 0);
                    O01 = __builtin_amdgcn_mfma_f32_16x16x32_bf16(pf, vf1, O01, 0, 0, 0);
                }
            }
        }
    }

    const int H_sp = branch ? 7 : RES;
    const int W_sp = branch ? RES : 7;
    #pragma unroll
    for (int t = 0; t < 2; ++t) if (t < nt) {
        float* ob = &ol[wv][0];
        #pragma unroll
        for (int r = 0; r < 4; ++r) {
            float s = t ? lsum1[r] : lsum0[r];
            s += __shfl_xor(s, 1); s += __shfl_xor(s, 2);
            s += __shfl_xor(s, 4); s += __shfl_xor(s, 8);
            const float inv = 1.f / s;
            const f32x4 Oa = t ? O10 : O00;
            const f32x4 Ob = t ? O11 : O01;
            ob[(g * 4 + r) * 36 + c16]      = Oa[r] * inv;
            ob[(g * 4 + r) * 36 + 16 + c16] = Ob[r] * inv;
        }
        const int r2 = lane >> 2, db = (lane & 3) * 8;
        const int n0 = (t0 + t) * 16 + r2;
        int i0, j0; nij(n0, branch, i0, j0);
        float acc[8];
        #pragma unroll
        for (int e = 0; e < 8; ++e) acc[e] = ob[r2 * 36 + db + e] + cb[head * 32 + db + e];
        #pragma unroll
        for (int dij = 0; dij < 9; ++dij) {
            const int di = dij / 3 - 1, dj = dij % 3 - 1;
            const int ii = i0 + di, jj = j0 + dj;
            if (ii >= 0 && ii < H_sp && jj >= 0 && jj < W_sp) {
                const ushort* vp = qkv + qkvB + (long long)((rowBase + ii) * RES + colBase + jj) * C3 + 256 + cbase + db;
                bf16x8 vv = *(const bf16x8*)vp;
                #pragma unroll
                for (int e = 0; e < 8; ++e)
                    acc[e] += cw[(head * 32 + db + e) * 9 + dij] * b2f((ushort)vv[e]);
            }
        }
        const long long Lq = (long long)(rowBase + i0) * RES + colBase + j0;
        ushort* op = att + ((long long)b * LTOK + Lq) * CDIM + cbase + db;
        bf16x8 ov;
        #pragma unroll
        for (int e = 0; e < 8; ++e) ov[e] = (short)f2b(acc[e]);
        *(bf16x8*)op = ov;
    }
}

// ---------------- K3: proj + bias + residual via MFMA (64 rows / block, no LDS) ----------------
__global__ __launch_bounds__(256) void k_proj(const ushort* __restrict__ att,
        const ushort* __restrict__ wproj_bf, const float* __restrict__ bproj,
        const float* __restrict__ x, float* __restrict__ xmid)
{
    const int tid = threadIdx.x;
    const int wv = tid >> 6, lane = tid & 63;
    const int c16 = lane & 15, g = lane >> 4;
    const long long row0 = (long long)blockIdx.x * 64;

    bf16x8 ab[4][4];
    #pragma unroll
    for (int mt = 0; mt < 4; ++mt)
        #pragma unroll
        for (int kc = 0; kc < 4; ++kc)
            ab[mt][kc] = *(const bf16x8*)&att[(row0 + mt * 16 + c16) * CDIM + kc * 32 + g * 8];

    #pragma unroll
    for (int tt = 0; tt < 2; ++tt) {
        const int n2 = wv * 32 + tt * 16;
        bf16x8 aw[4];
        #pragma unroll
        for (int kc = 0; kc < 4; ++kc)
            aw[kc] = *(const bf16x8*)&wproj_bf[(n2 + c16) * CDIM + kc * 32 + g * 8];
        f32x4 acc[4] = {{0.f,0.f,0.f,0.f},{0.f,0.f,0.f,0.f},{0.f,0.f,0.f,0.f},{0.f,0.f,0.f,0.f}};
        #pragma unroll
        for (int kc = 0; kc < 4; ++kc)
            #pragma unroll
            for (int mt = 0; mt < 4; ++mt)
                acc[mt] = __builtin_amdgcn_mfma_f32_16x16x32_bf16(aw[kc], ab[mt][kc], acc[mt], 0, 0, 0);
        const int col = n2 + g * 4;
        float4 bb = *(const float4*)&bproj[col];
        #pragma unroll
        for (int mt = 0; mt < 4; ++mt) {
            const long long row = row0 + mt * 16 + c16;
            float4 xv = *(const float4*)&x[row * CDIM + col];
            float4 o;
            o.x = acc[mt][0] + xv.x + bb.x;
            o.y = acc[mt][1] + xv.y + bb.y;
            o.z = acc[mt][2] + xv.z + bb.z;
            o.w = acc[mt][3] + xv.w + bb.w;
            *(float4*)&xmid[row * CDIM + col] = o;
        }
    }
}

// ---------------- K4: LN2 + FC1 + GELU + FC2 + residual via MFMA (64 rows / block) ----------------
__global__ __launch_bounds__(256) void k_mlp(const float* __restrict__ xmid,
        const float* __restrict__ g2, const float* __restrict__ b2,
        const ushort* __restrict__ w1bf, const float* __restrict__ bfc1,
        const ushort* __restrict__ w2bf, const float* __restrict__ bfc2,
        float* __restrict__ out)
{
    __shared__ ushort ys[64][136];   // 17,408 B
    __shared__ ushort hs[64][264];   // 33,792 B (half of FC1 output: 256 cols + 8 pad)
    const int tid = threadIdx.x;
    const long long row0 = (long long)blockIdx.x * 64;

    // LN2: 4 threads per row, 32 elems each
    {
        const int r = tid >> 2, t4 = tid & 3;
        const float* xr = xmid + (row0 + r) * CDIM + t4 * 32;
        float4 a[8];
        #pragma unroll
        for (int i = 0; i < 8; ++i) a[i] = ((const float4*)xr)[i];
        float s = 0.f, s2 = 0.f;
        #pragma unroll
        for (int i = 0; i < 8; ++i) {
            s  += a[i].x + a[i].y + a[i].z + a[i].w;
            s2 += a[i].x*a[i].x + a[i].y*a[i].y + a[i].z*a[i].z + a[i].w*a[i].w;
        }
        s += __shfl_xor(s, 1, 4); s2 += __shfl_xor(s2, 1, 4);
        s += __shfl_xor(s, 2, 4); s2 += __shfl_xor(s2, 2, 4);
        const float mean = s * (1.f / 128.f);
        const float var = s2 * (1.f / 128.f) - mean * mean;
        const float rs = rsqrtf(var + 1e-5f);
        #pragma unroll
        for (int i = 0; i < 8; i += 2) {
            ushort4 w0, w1;
            float4 ga = *(const float4*)(g2 + t4 * 32 + i * 4);
            float4 ba = *(const float4*)(b2 + t4 * 32 + i * 4);
            float4 gb = *(const float4*)(g2 + t4 * 32 + i * 4 + 4);
            float4 bb = *(const float4*)(b2 + t4 * 32 + i * 4 + 4);
            w0.x = f2b((a[i].x - mean) * rs * ga.x + ba.x);
            w0.y = f2b((a[i].y - mean) * rs * ga.y + ba.y);
            w0.z = f2b((a[i].z - mean) * rs * ga.z + ba.z);
            w0.w = f2b((a[i].w - mean) * rs * ga.w + ba.w);
            w1.x = f2b((a[i+1].x - mean) * rs * gb.x + bb.x);
            w1.y = f2b((a[i+1].y - mean) * rs * gb.y + bb.y);
            w1.z = f2b((a[i+1].z - mean) * rs * gb.z + bb.z);
            w1.w = f2b((a[i+1].w - mean) * rs * gb.w + bb.w);
            *(ushort4*)&ys[r][t4 * 32 + i * 4]     = w0;
            *(ushort4*)&ys[r][t4 * 32 + i * 4 + 4] = w1;
        }
    }
    __syncthreads();

    const int wv = tid >> 6, lane = tid & 63;
    const int c16 = lane & 15, g = lane >> 4;

    // hoist LN'd activations: 4 m-tiles x 4 k-chunks, reused for all FC1 n-tiles
    bf16x8 yb[4][4];
    #pragma unroll
    for (int mt = 0; mt < 4; ++mt)
        #pragma unroll
        for (int kc = 0; kc < 4; ++kc)
            yb[mt][kc] = *(const bf16x8*)&ys[mt * 16 + c16][kc * 32 + g * 8];

    f32x4 acc2[2][4];
    #pragma unroll
    for (int tt = 0; tt < 2; ++tt)
        #pragma unroll
        for (int mt = 0; mt < 4; ++mt)
            acc2[tt][mt] = (f32x4){0.f, 0.f, 0.f, 0.f};

    #pragma unroll
    for (int half = 0; half < 2; ++half) {
        // FC1 half: compute h cols [half*256, half*256+256), wave wv owns 64 of them
        #pragma unroll
        for (int t = 0; t < 4; ++t) {
            const int n0g = half * 256 + wv * 64 + t * 16;   // global h col base
            bf16x8 aw[4];
            #pragma unroll
            for (int kc = 0; kc < 4; ++kc)
                aw[kc] = *(const bf16x8*)&w1bf[(n0g + c16) * CDIM + kc * 32 + g * 8];
            float4 b1v = *(const float4*)&bfc1[n0g + g * 4];
            #pragma unroll
            for (int mt = 0; mt < 4; ++mt) {
                f32x4 a = {0.f, 0.f, 0.f, 0.f};
                #pragma unroll
                for (int kc = 0; kc < 4; ++kc)
                    a = __builtin_amdgcn_mfma_f32_16x16x32_bf16(aw[kc], yb[mt][kc], a, 0, 0, 0);
                ushort4 sv;
                sv.x = f2b(gelu_f(a[0] + b1v.x));
                sv.y = f2b(gelu_f(a[1] + b1v.y));
                sv.z = f2b(gelu_f(a[2] + b1v.z));
                sv.w = f2b(gelu_f(a[3] + b1v.w));
                *(ushort4*)&hs[mt * 16 + c16][wv * 64 + t * 16 + g * 4] = sv;
            }
        }
        __syncthreads();

        // FC2 partial over this half's 256 h cols
        #pragma unroll
        for (int kc = 0; kc < 8; ++kc) {
            bf16x8 hb[4];
            #pragma unroll
            for (int mt = 0; mt < 4; ++mt)
                hb[mt] = *(const bf16x8*)&hs[mt * 16 + c16][kc * 32 + g * 8];
            #pragma unroll
            for (int tt = 0; tt < 2; ++tt) {
                bf16x8 aw2 = *(const bf16x8*)&w2bf[(wv * 32 + tt * 16 + c16) * 512 + half * 256 + kc * 32 + g * 8];
                #pragma unroll
                for (int mt = 0; mt < 4; ++mt)
                    acc2[tt][mt] = __builtin_amdgcn_mfma_f32_16x16x32_bf16(aw2, hb[mt], acc2[tt][mt], 0, 0, 0);
            }
        }
        if (half == 0) __syncthreads();   // before FC1 overwrites hs
    }

    // epilogue: bias + residual, float4 stores
    #pragma unroll
    for (int tt = 0; tt < 2; ++tt) {
        const int col = wv * 32 + tt * 16 + g * 4;
        float4 bb = *(const float4*)&bfc2[col];
        #pragma unroll
        for (int mt = 0; mt < 4; ++mt) {
            const long long row = row0 + mt * 16 + c16;
            float4 res = *(const float4*)&xmid[row * CDIM + col];
            float4 o;
            o.x = acc2[tt][mt][0] + res.x + bb.x;
            o.y = acc2[tt][mt][1] + res.y + bb.y;
            o.z = acc2[tt][mt][2] + res.z + bb.z;
            o.w = acc2[tt][mt][3] + res.w + bb.w;
            *(float4*)&out[row * CDIM + col] = o;
        }
    }
}

extern "C" void kernel_launch(void* const* d_in, const int* in_sizes, int n_in,
                              void* d_out, int out_size, void* d_ws, size_t ws_size,
                              hipStream_t stream) {
    const float* x     = (const float*)d_in[0];
    const float* g1    = (const float*)d_in[1];
    const float* b1    = (const float*)d_in[2];
    const float* wqkv  = (const float*)d_in[3];
    const float* cw0   = (const float*)d_in[4];
    const float* cb0   = (const float*)d_in[5];
    const float* cw1   = (const float*)d_in[6];
    const float* cb1   = (const float*)d_in[7];
    const float* wproj = (const float*)d_in[8];
    const float* bproj = (const float*)d_in[9];
    const float* g2    = (const float*)d_in[10];
    const float* b2    = (const float*)d_in[11];
    const float* wfc1  = (const float*)d_in[12];
    const float* bfc1  = (const float*)d_in[13];
    const float* wfc2  = (const float*)d_in[14];
    const float* bfc2  = (const float*)d_in[15];

    char* wsb = (char*)d_ws;
    ushort* qkv_bf   = (ushort*)wsb;                           // 19,267,584 B
    ushort* att_bf   = (ushort*)(wsb + 19267584);              //  6,422,528 B
    float*  xmid     = (float*) (wsb + 19267584 + 6422528);    // 12,845,056 B
    char*   wbase    = wsb + 38535168;
    ushort* wqkv_bf  = (ushort*)(wbase);                       // 98,304 B
    ushort* wproj_bf = (ushort*)(wbase + 98304);               // 32,768 B
    ushort* wfc1_bf  = (ushort*)(wbase + 98304 + 32768);       // 131,072 B
    ushort* wfc2_bf  = (ushort*)(wbase + 98304 + 32768 + 131072);

    float* out = (float*)d_out;

    k_cvt<<<192, 256, 0, stream>>>(wqkv, wproj, wfc1, wfc2, wqkv_bf, wproj_bf, wfc1_bf, wfc2_bf);
    k_ln_qkv<<<NROWS / 32, 256, 0, stream>>>(x, g1, b1, wqkv_bf, qkv_bf);
    k_attn_mfma<<<dim3(128, 7), 256, 0, stream>>>(qkv_bf, cw0, cb0, cw1, cb1, att_bf);
    k_proj<<<NROWS / 64, 256, 0, stream>>>(att_bf, wproj_bf, bproj, x, xmid);
    k_mlp<<<NROWS / 64, 256, 0, stream>>>(xmid, g2, b2, wfc1_bf, bfc1, wfc2_bf, bfc2, out);
}

// Round 5
// 115.561 us; speedup vs baseline: 5.4254x; 1.0919x over previous
//
#include <hip/hip_runtime.h>
#include <cstdint>

#define LTOK 12544
#define BATCH 2
#define CDIM 128
#define C3 384
#define RES 112
#define NROWS (BATCH * LTOK)  // 25088
#define SCALE 0.17677669529663687f  // 1/sqrt(32)

typedef __attribute__((ext_vector_type(8))) short bf16x8;
typedef __attribute__((ext_vector_type(4))) float f32x4;

__device__ inline ushort f2b(float f) {
    union { float f; unsigned u; } v; v.f = f;
    unsigned r = (v.u + 0x7FFFu + ((v.u >> 16) & 1u)) >> 16;
    return (ushort)r;
}
__device__ inline float b2f(ushort u) {
    union { float f; unsigned u; } v; v.u = ((unsigned)u) << 16; return v.f;
}
__device__ inline float gelu_f(float a) {
    return 0.5f * a * (1.0f + erff(a * 0.70710678118654752f));
}

// map window-local token n -> (i, j); branch 0: W_sp=7, branch 1: W_sp=112
__device__ inline void nij(int n, int branch, int& i, int& j) {
    if (branch == 0) { i = n / 7; j = n - i * 7; }
    else             { i = n / 112; j = n - i * 112; }
}

// ---------------- K0: convert all weights to bf16 ----------------
__global__ __launch_bounds__(256) void k_cvt(const float* __restrict__ w0, const float* __restrict__ w1,
        const float* __restrict__ w2, const float* __restrict__ w3,
        ushort* __restrict__ o0, ushort* __restrict__ o1,
        ushort* __restrict__ o2, ushort* __restrict__ o3)
{
    int idx = blockIdx.x * 256 + threadIdx.x;  // vec4 index
    const float* src; ushort* dst; int vi;
    if      (idx < 12288) { src = w0; dst = o0; vi = idx; }
    else if (idx < 16384) { src = w1; dst = o1; vi = idx - 12288; }
    else if (idx < 32768) { src = w2; dst = o2; vi = idx - 16384; }
    else                  { src = w3; dst = o3; vi = idx - 32768; }
    float4 v = ((const float4*)src)[vi];
    ushort4 r; r.x = f2b(v.x); r.y = f2b(v.y); r.z = f2b(v.z); r.w = f2b(v.w);
    ((ushort4*)dst)[vi] = r;
}

// ---------------- K1: LN1 + QKV GEMM via MFMA (32 rows / 256-thread block) ----------------
__global__ __launch_bounds__(256) void k_ln_qkv(const float* __restrict__ x,
        const float* __restrict__ g1, const float* __restrict__ b1,
        const ushort* __restrict__ wqkv_bf, ushort* __restrict__ qkv)
{
    __shared__ ushort ys[32][136];
    const int tid = threadIdx.x;
    const long long row0 = (long long)blockIdx.x * 32;

    {
        const int r = tid >> 3, l8 = tid & 7;
        const float* xr = x + (row0 + r) * CDIM + l8 * 16;
        float4 a[4];
        #pragma unroll
        for (int i = 0; i < 4; ++i) a[i] = ((const float4*)xr)[i];
        float s = 0.f, s2 = 0.f;
        #pragma unroll
        for (int i = 0; i < 4; ++i) {
            s  += a[i].x + a[i].y + a[i].z + a[i].w;
            s2 += a[i].x*a[i].x + a[i].y*a[i].y + a[i].z*a[i].z + a[i].w*a[i].w;
        }
        #pragma unroll
        for (int m = 4; m >= 1; m >>= 1) { s += __shfl_xor(s, m, 8); s2 += __shfl_xor(s2, m, 8); }
        const float mean = s * (1.f / 128.f);
        const float var = s2 * (1.f / 128.f) - mean * mean;
        const float rs = rsqrtf(var + 1e-5f);
        ushort4 w[4];
        #pragma unroll
        for (int i = 0; i < 4; ++i) {
            float4 gg = *(const float4*)(g1 + l8 * 16 + i * 4);
            float4 bb = *(const float4*)(b1 + l8 * 16 + i * 4);
            w[i].x = f2b((a[i].x - mean) * rs * gg.x + bb.x);
            w[i].y = f2b((a[i].y - mean) * rs * gg.y + bb.y);
            w[i].z = f2b((a[i].z - mean) * rs * gg.z + bb.z);
            w[i].w = f2b((a[i].w - mean) * rs * gg.w + bb.w);
        }
        #pragma unroll
        for (int i = 0; i < 4; ++i) *(ushort4*)&ys[r][l8 * 16 + i * 4] = w[i];
    }
    __syncthreads();

    const int wv = tid >> 6, lane = tid & 63;
    const int c16 = lane & 15, g = lane >> 4;

    bf16x8 yb[2][4];
    #pragma unroll
    for (int mt = 0; mt < 2; ++mt)
        #pragma unroll
        for (int kc = 0; kc < 4; ++kc)
            yb[mt][kc] = *(const bf16x8*)&ys[mt * 16 + c16][kc * 32 + g * 8];

    #pragma unroll
    for (int t = 0; t < 6; ++t) {
        const int n0 = wv * 96 + t * 16;
        bf16x8 aw[4];
        #pragma unroll
        for (int kc = 0; kc < 4; ++kc)
            aw[kc] = *(const bf16x8*)&wqkv_bf[(n0 + c16) * CDIM + kc * 32 + g * 8];
        #pragma unroll
        for (int mt = 0; mt < 2; ++mt) {
            f32x4 acc = {0.f, 0.f, 0.f, 0.f};
            #pragma unroll
            for (int kc = 0; kc < 4; ++kc)
                acc = __builtin_amdgcn_mfma_f32_16x16x32_bf16(aw[kc], yb[mt][kc], acc, 0, 0, 0);
            ushort4 sv;
            sv.x = f2b(acc[0]); sv.y = f2b(acc[1]); sv.z = f2b(acc[2]); sv.w = f2b(acc[3]);
            *(ushort4*)&qkv[(row0 + mt * 16 + c16) * C3 + n0 + g * 4] = sv;
        }
    }
}

// ---------------- K2: windowed attention + LEPE via bf16 MFMA (unchanged) ----------------
__global__ __launch_bounds__(256) void k_attn_mfma(const ushort* __restrict__ qkv,
        const float* __restrict__ cw0, const float* __restrict__ cb0,
        const float* __restrict__ cw1, const float* __restrict__ cb1,
        ushort* __restrict__ att)
{
    __shared__ __align__(16) ushort ks[112 * 40];
    __shared__ __align__(16) ushort vt[32 * 136];
    __shared__ __align__(16) ushort pl[4][16 * 40];
    __shared__ __align__(16) float  ol[4][16 * 36];

    const int tid = threadIdx.x;
    const int wv = tid >> 6, lane = tid & 63;
    const int g = lane >> 4, c16 = lane & 15;

    const int wh = blockIdx.x;
    const int branch = wh >> 6;
    const int idx = wh & 63;
    const int win = idx >> 1, head = idx & 1;
    const int b = win >> 4, w = win & 15;
    const int rowBase = branch ? w * 7 : 0;
    const int colBase = branch ? 0 : w * 7;
    const float* cw = branch ? cw1 : cw0;
    const float* cb = branch ? cb1 : cb0;
    const int cbase = branch * 64 + head * 32;
    const long long qkvB = (long long)b * LTOK * C3;

    {
        const int row = tid >> 3, cwd = tid & 7;
        *(unsigned*)&vt[row * 136 + 112 + cwd * 2] = 0u;
    }

    const int t0 = blockIdx.y * 7 + 2 * wv;
    const int nt = (2 * wv + 1 < 7) ? 2 : 1;

    bf16x8 qf[2];
    #pragma unroll
    for (int t = 0; t < 2; ++t) if (t < nt) {
        int n = (t0 + t) * 16 + c16;
        int i, j; nij(n, branch, i, j);
        const ushort* qp = qkv + qkvB + (long long)((rowBase + i) * RES + colBase + j) * C3 + cbase + g * 8;
        bf16x8 qq = *(const bf16x8*)qp;
        #pragma unroll
        for (int e = 0; e < 8; ++e) qq[e] = (short)f2b(b2f((ushort)qq[e]) * SCALE);
        qf[t] = qq;
    }

    f32x4 O00 = {0.f,0.f,0.f,0.f}, O01 = {0.f,0.f,0.f,0.f};
    f32x4 O10 = {0.f,0.f,0.f,0.f}, O11 = {0.f,0.f,0.f,0.f};
    float lsum0[4] = {0.f,0.f,0.f,0.f};
    float lsum1[4] = {0.f,0.f,0.f,0.f};

    for (int cc = 0; cc < 7; ++cc) {
        __syncthreads();
        for (int u = tid; u < 448; u += 256) {
            const int key = u >> 2, d8 = (u & 3) * 8;
            const int n = cc * 112 + key;
            int i, j; nij(n, branch, i, j);
            const ushort* base = qkv + qkvB + (long long)((rowBase + i) * RES + colBase + j) * C3 + cbase + d8;
            bf16x8 kk = *(const bf16x8*)(base + 128);
            bf16x8 vv = *(const bf16x8*)(base + 256);
            *(bf16x8*)&ks[key * 40 + d8] = kk;
            #pragma unroll
            for (int e = 0; e < 8; ++e) vt[(d8 + e) * 136 + key] = (ushort)vv[e];
        }
        __syncthreads();

        #pragma unroll
        for (int p = 0; p < 4; ++p) {
            bf16x8 kf0 = *(const bf16x8*)&ks[(p * 32 + c16) * 40 + g * 8];
            bf16x8 kf1;
            if (p < 3) kf1 = *(const bf16x8*)&ks[(p * 32 + 16 + c16) * 40 + g * 8];
            bf16x8 vf0 = *(const bf16x8*)&vt[c16 * 136 + p * 32 + g * 8];
            bf16x8 vf1 = *(const bf16x8*)&vt[(16 + c16) * 136 + p * 32 + g * 8];
            ushort* pb = &pl[wv][0];

            #pragma unroll
            for (int t = 0; t < 2; ++t) if (t < nt) {
                const bf16x8 qq = t ? qf[1] : qf[0];
                f32x4 z = {0.f,0.f,0.f,0.f};
                f32x4 S0 = __builtin_amdgcn_mfma_f32_16x16x32_bf16(qq, kf0, z, 0, 0, 0);
                f32x4 S1 = z;
                if (p < 3) S1 = __builtin_amdgcn_mfma_f32_16x16x32_bf16(qq, kf1, z, 0, 0, 0);
                ushort pw0[4], pw1[4];
                #pragma unroll
                for (int r = 0; r < 4; ++r) {
                    float e0 = __expf(S0[r]);
                    if (t) lsum1[r] += e0; else lsum0[r] += e0;
                    pw0[r] = f2b(e0);
                    if (p < 3) {
                        float e1 = __expf(S1[r]);
                        if (t) lsum1[r] += e1; else lsum0[r] += e1;
                        pw1[r] = f2b(e1);
                    } else pw1[r] = 0;
                }
                #pragma unroll
                for (int r = 0; r < 4; ++r) {
                    pb[(g * 4 + r) * 40 + c16]      = pw0[r];
                    pb[(g * 4 + r) * 40 + 16 + c16] = pw1[r];
                }
                bf16x8 pf = *(const bf16x8*)&pb[c16 * 40 + g * 8];
                if (t) {
                    O10 = __builtin_amdgcn_mfma_f32_16x16x32_bf16(pf, vf0, O10, 0, 0, 0);
                    O11 = __builtin_amdgcn_mfma_f32_16x16x32_bf16(pf, vf1, O11, 0, 0, 0);
                } else {
                    O00 = __builtin_amdgcn_mfma_f32_16x16x32_bf16(pf, vf0, O00, 0, 0, 0);
                    O01 = __builtin_amdgcn_mfma_f32_16x16x32_bf16(pf, vf1, O01, 0, 0, 0);
                }
            }
        }
    }

    const int H_sp = branch ? 7 : RES;
    const int W_sp = branch ? RES : 7;
    #pragma unroll
    for (int t = 0; t < 2; ++t) if (t < nt) {
        float* ob = &ol[wv][0];
        #pragma unroll
        for (int r = 0; r < 4; ++r) {
            float s = t ? lsum1[r] : lsum0[r];
            s += __shfl_xor(s, 1); s += __shfl_xor(s, 2);
            s += __shfl_xor(s, 4); s += __shfl_xor(s, 8);
            const float inv = 1.f / s;
            const f32x4 Oa = t ? O10 : O00;
            const f32x4 Ob = t ? O11 : O01;
            ob[(g * 4 + r) * 36 + c16]      = Oa[r] * inv;
            ob[(g * 4 + r) * 36 + 16 + c16] = Ob[r] * inv;
        }
        const int r2 = lane >> 2, db = (lane & 3) * 8;
        const int n0 = (t0 + t) * 16 + r2;
        int i0, j0; nij(n0, branch, i0, j0);
        float acc[8];
        #pragma unroll
        for (int e = 0; e < 8; ++e) acc[e] = ob[r2 * 36 + db + e] + cb[head * 32 + db + e];
        #pragma unroll
        for (int dij = 0; dij < 9; ++dij) {
            const int di = dij / 3 - 1, dj = dij % 3 - 1;
            const int ii = i0 + di, jj = j0 + dj;
            if (ii >= 0 && ii < H_sp && jj >= 0 && jj < W_sp) {
                const ushort* vp = qkv + qkvB + (long long)((rowBase + ii) * RES + colBase + jj) * C3 + 256 + cbase + db;
                bf16x8 vv = *(const bf16x8*)vp;
                #pragma unroll
                for (int e = 0; e < 8; ++e)
                    acc[e] += cw[(head * 32 + db + e) * 9 + dij] * b2f((ushort)vv[e]);
            }
        }
        const long long Lq = (long long)(rowBase + i0) * RES + colBase + j0;
        ushort* op = att + ((long long)b * LTOK + Lq) * CDIM + cbase + db;
        bf16x8 ov;
        #pragma unroll
        for (int e = 0; e < 8; ++e) ov[e] = (short)f2b(acc[e]);
        *(bf16x8*)op = ov;
    }
}

// ---------------- K3: fused proj + residual + LN2 + FC1 + GELU + FC2 + residual ----------------
// 32 rows / 256-thread block; xmid residual lives in registers; xs aliased with hs.
__global__ __launch_bounds__(256) void k_pmlp(const ushort* __restrict__ att,
        const ushort* __restrict__ wproj_bf, const float* __restrict__ bproj,
        const float* __restrict__ x,
        const float* __restrict__ g2, const float* __restrict__ b2,
        const ushort* __restrict__ w1bf, const float* __restrict__ bfc1,
        const ushort* __restrict__ w2bf, const float* __restrict__ bfc2,
        float* __restrict__ out)
{
    __shared__ union {
        float  xs[32][132];   // 16,896 B (proj result, dead after LN)
        ushort hs[32][264];   // 16,896 B (FC1 half output)
    } u;
    __shared__ ushort ys[32][136];   // 8,704 B
    const int tid = threadIdx.x;
    const int wv = tid >> 6, lane = tid & 63;
    const int c16 = lane & 15, g = lane >> 4;
    const long long row0 = (long long)blockIdx.x * 32;

    // ---- proj (att @ wproj^T) + bias + x  -> resid (regs) + xs (LDS) ----
    f32x4 resid[2][2];
    {
        bf16x8 ab[2][4];
        #pragma unroll
        for (int mt = 0; mt < 2; ++mt)
            #pragma unroll
            for (int kc = 0; kc < 4; ++kc)
                ab[mt][kc] = *(const bf16x8*)&att[(row0 + mt * 16 + c16) * CDIM + kc * 32 + g * 8];

        #pragma unroll
        for (int tt = 0; tt < 2; ++tt) {
            const int n2 = wv * 32 + tt * 16;
            bf16x8 aw[4];
            #pragma unroll
            for (int kc = 0; kc < 4; ++kc)
                aw[kc] = *(const bf16x8*)&wproj_bf[(n2 + c16) * CDIM + kc * 32 + g * 8];
            const int col = n2 + g * 4;
            float4 bb = *(const float4*)&bproj[col];
            #pragma unroll
            for (int mt = 0; mt < 2; ++mt) {
                f32x4 a = {0.f, 0.f, 0.f, 0.f};
                #pragma unroll
                for (int kc = 0; kc < 4; ++kc)
                    a = __builtin_amdgcn_mfma_f32_16x16x32_bf16(aw[kc], ab[mt][kc], a, 0, 0, 0);
                float4 xv = *(const float4*)&x[(row0 + mt * 16 + c16) * CDIM + col];
                f32x4 r;
                r[0] = a[0] + xv.x + bb.x;
                r[1] = a[1] + xv.y + bb.y;
                r[2] = a[2] + xv.z + bb.z;
                r[3] = a[3] + xv.w + bb.w;
                resid[tt][mt] = r;
                *(float4*)&u.xs[mt * 16 + c16][col] = make_float4(r[0], r[1], r[2], r[3]);
            }
        }
    }
    __syncthreads();

    // ---- LN2 on xs -> ys (bf16) ----
    {
        const int r = tid >> 3, l8 = tid & 7;
        float4 a[4];
        #pragma unroll
        for (int i = 0; i < 4; ++i) a[i] = *(const float4*)&u.xs[r][l8 * 16 + i * 4];
        float s = 0.f, s2 = 0.f;
        #pragma unroll
        for (int i = 0; i < 4; ++i) {
            s  += a[i].x + a[i].y + a[i].z + a[i].w;
            s2 += a[i].x*a[i].x + a[i].y*a[i].y + a[i].z*a[i].z + a[i].w*a[i].w;
        }
        #pragma unroll
        for (int m = 4; m >= 1; m >>= 1) { s += __shfl_xor(s, m, 8); s2 += __shfl_xor(s2, m, 8); }
        const float mean = s * (1.f / 128.f);
        const float var = s2 * (1.f / 128.f) - mean * mean;
        const float rs = rsqrtf(var + 1e-5f);
        #pragma unroll
        for (int i = 0; i < 4; ++i) {
            float4 gg = *(const float4*)(g2 + l8 * 16 + i * 4);
            float4 bb = *(const float4*)(b2 + l8 * 16 + i * 4);
            ushort4 w;
            w.x = f2b((a[i].x - mean) * rs * gg.x + bb.x);
            w.y = f2b((a[i].y - mean) * rs * gg.y + bb.y);
            w.z = f2b((a[i].z - mean) * rs * gg.z + bb.z);
            w.w = f2b((a[i].w - mean) * rs * gg.w + bb.w);
            *(ushort4*)&ys[r][l8 * 16 + i * 4] = w;
        }
    }
    __syncthreads();   // ys ready; xs fully consumed (hs may now overwrite)

    bf16x8 yb[2][4];
    #pragma unroll
    for (int mt = 0; mt < 2; ++mt)
        #pragma unroll
        for (int kc = 0; kc < 4; ++kc)
            yb[mt][kc] = *(const bf16x8*)&ys[mt * 16 + c16][kc * 32 + g * 8];

    f32x4 acc2[2][2];
    #pragma unroll
    for (int tt = 0; tt < 2; ++tt)
        #pragma unroll
        for (int mt = 0; mt < 2; ++mt)
            acc2[tt][mt] = (f32x4){0.f, 0.f, 0.f, 0.f};

    #pragma unroll
    for (int half = 0; half < 2; ++half) {
        // FC1 half: h cols [half*256, half*256+256); wave owns 64 (4 n-tiles)
        #pragma unroll
        for (int t = 0; t < 4; ++t) {
            const int n0g = half * 256 + wv * 64 + t * 16;
            bf16x8 aw[4];
            #pragma unroll
            for (int kc = 0; kc < 4; ++kc)
                aw[kc] = *(const bf16x8*)&w1bf[(n0g + c16) * CDIM + kc * 32 + g * 8];
            float4 b1v = *(const float4*)&bfc1[n0g + g * 4];
            #pragma unroll
            for (int mt = 0; mt < 2; ++mt) {
                f32x4 a = {0.f, 0.f, 0.f, 0.f};
                #pragma unroll
                for (int kc = 0; kc < 4; ++kc)
                    a = __builtin_amdgcn_mfma_f32_16x16x32_bf16(aw[kc], yb[mt][kc], a, 0, 0, 0);
                ushort4 sv;
                sv.x = f2b(gelu_f(a[0] + b1v.x));
                sv.y = f2b(gelu_f(a[1] + b1v.y));
                sv.z = f2b(gelu_f(a[2] + b1v.z));
                sv.w = f2b(gelu_f(a[3] + b1v.w));
                *(ushort4*)&u.hs[mt * 16 + c16][wv * 64 + t * 16 + g * 4] = sv;
            }
        }
        __syncthreads();

        // FC2 partial over this half's 256 h cols
        #pragma unroll
        for (int kc = 0; kc < 8; ++kc) {
            bf16x8 hb[2];
            #pragma unroll
            for (int mt = 0; mt < 2; ++mt)
                hb[mt] = *(const bf16x8*)&u.hs[mt * 16 + c16][kc * 32 + g * 8];
            #pragma unroll
            for (int tt = 0; tt < 2; ++tt) {
                bf16x8 aw2 = *(const bf16x8*)&w2bf[(wv * 32 + tt * 16 + c16) * 512 + half * 256 + kc * 32 + g * 8];
                #pragma unroll
                for (int mt = 0; mt < 2; ++mt)
                    acc2[tt][mt] = __builtin_amdgcn_mfma_f32_16x16x32_bf16(aw2, hb[mt], acc2[tt][mt], 0, 0, 0);
            }
        }
        if (half == 0) __syncthreads();   // before FC1 overwrites hs
    }

    // ---- epilogue: out = acc2 + resid(reg) + bfc2 ----
    #pragma unroll
    for (int tt = 0; tt < 2; ++tt) {
        const int col = wv * 32 + tt * 16 + g * 4;
        float4 bb = *(const float4*)&bfc2[col];
        #pragma unroll
        for (int mt = 0; mt < 2; ++mt) {
            const long long row = row0 + mt * 16 + c16;
            float4 o;
            o.x = acc2[tt][mt][0] + resid[tt][mt][0] + bb.x;
            o.y = acc2[tt][mt][1] + resid[tt][mt][1] + bb.y;
            o.z = acc2[tt][mt][2] + resid[tt][mt][2] + bb.z;
            o.w = acc2[tt][mt][3] + resid[tt][mt][3] + bb.w;
            *(float4*)&out[row * CDIM + col] = o;
        }
    }
}

extern "C" void kernel_launch(void* const* d_in, const int* in_sizes, int n_in,
                              void* d_out, int out_size, void* d_ws, size_t ws_size,
                              hipStream_t stream) {
    const float* x     = (const float*)d_in[0];
    const float* g1    = (const float*)d_in[1];
    const float* b1    = (const float*)d_in[2];
    const float* wqkv  = (const float*)d_in[3];
    const float* cw0   = (const float*)d_in[4];
    const float* cb0   = (const float*)d_in[5];
    const float* cw1   = (const float*)d_in[6];
    const float* cb1   = (const float*)d_in[7];
    const float* wproj = (const float*)d_in[8];
    const float* bproj = (const float*)d_in[9];
    const float* g2    = (const float*)d_in[10];
    const float* b2    = (const float*)d_in[11];
    const float* wfc1  = (const float*)d_in[12];
    const float* bfc1  = (const float*)d_in[13];
    const float* wfc2  = (const float*)d_in[14];
    const float* bfc2  = (const float*)d_in[15];

    char* wsb = (char*)d_ws;
    ushort* qkv_bf   = (ushort*)wsb;                           // 19,267,584 B
    ushort* att_bf   = (ushort*)(wsb + 19267584);              //  6,422,528 B
    char*   wbase    = wsb + 19267584 + 6422528;
    ushort* wqkv_bf  = (ushort*)(wbase);                       // 98,304 B
    ushort* wproj_bf = (ushort*)(wbase + 98304);               // 32,768 B
    ushort* wfc1_bf  = (ushort*)(wbase + 98304 + 32768);       // 131,072 B
    ushort* wfc2_bf  = (ushort*)(wbase + 98304 + 32768 + 131072);

    float* out = (float*)d_out;

    k_cvt<<<192, 256, 0, stream>>>(wqkv, wproj, wfc1, wfc2, wqkv_bf, wproj_bf, wfc1_bf, wfc2_bf);
    k_ln_qkv<<<NROWS / 32, 256, 0, stream>>>(x, g1, b1, wqkv_bf, qkv_bf);
    k_attn_mfma<<<dim3(128, 7), 256, 0, stream>>>(qkv_bf, cw0, cb0, cw1, cb1, att_bf);
    k_pmlp<<<NROWS / 32, 256, 0, stream>>>(att_bf, wproj_bf, bproj, x, g2, b2,
                                           wfc1_bf, bfc1, wfc2_bf, bfc2, out);
}